// Round 14
// baseline (159.738 us; speedup 1.0000x reference)
//
#include <hip/hip_runtime.h>
#include <math.h>

#define EPSV 1e-5f

typedef __attribute__((ext_vector_type(8))) _Float16 f16x8;
typedef __attribute__((ext_vector_type(4))) _Float16 f16x4;
typedef __attribute__((ext_vector_type(4))) float f32x4;

typedef __attribute__((address_space(1))) const unsigned int as1_u32;
typedef __attribute__((address_space(3))) unsigned int as3_u32;

static __device__ __forceinline__ unsigned packh2(float a, float b) {
  auto v = __builtin_amdgcn_cvt_pkrtz(a, b);  // __fp16 ext_vector(2)
  return __builtin_bit_cast(unsigned, v);
}

// ---------------- pack weights fp32 -> fp16 [4][*] (tw,pw,gw: 128x256; rw: 256x128)
__global__ __launch_bounds__(256) void pack_w(const float* __restrict__ tw,
                                              const float* __restrict__ pw,
                                              const float* __restrict__ gw,
                                              const float* __restrict__ rw,
                                              _Float16* __restrict__ w16) {
  int i = blockIdx.x * 256 + threadIdx.x;  // 131072
  const float* s = i < 32768 ? tw : (i < 65536 ? pw : (i < 98304 ? gw : rw));
  w16[i] = (_Float16)s[i & 32767];
}

// ---------------- pack x,y fp32 [n][c][p] -> fp16 transposed [src][n][p][c]
__global__ __launch_bounds__(256) void pack_xy(const float* __restrict__ x,
                                               const float* __restrict__ y,
                                               _Float16* __restrict__ xt) {
  const int n = blockIdx.y, s = blockIdx.z;
  const int g = blockIdx.x * 256 + threadIdx.x;  // 131072 per (n,s)
  const int p = g & 4095, c8 = g >> 12;          // c8 0..31
  const float* src = (s ? y : x) + ((size_t)n * 256 + c8 * 8) * 4096 + p;
  f16x8 v;
#pragma unroll
  for (int j = 0; j < 8; ++j) v[j] = (_Float16)src[(size_t)j * 4096];
  *(f16x8*)(xt + ((size_t)(s * 4 + n) * 4096 + p) * 256 + c8 * 8) = v;
}

// ---------------- projections via MFMA.
// pr 0 (theta): -> [p][ci]; pr 1 (phi): -> [p][ci]; pr 2 (g): -> blocked [p/32][ci][32]
__global__ __launch_bounds__(256) void proj_kernel(
    const _Float16* __restrict__ xt, const _Float16* __restrict__ w16,
    const float* __restrict__ tb, const float* __restrict__ pb,
    const float* __restrict__ gb, _Float16* __restrict__ th16,
    _Float16* __restrict__ ph16, _Float16* __restrict__ g16) {
  const int ptile = blockIdx.x;  // 32 tiles of 128 positions
  const int z = blockIdx.y;      // 12 = 3 pr * 4 n
  const int pr = z >> 2, n = z & 3;
  const int p0 = ptile * 128;
  const int tid = threadIdx.x, wv = tid >> 6, lane = tid & 63, lg = lane >> 4, lr = lane & 15;

  __shared__ __align__(16) char sB[65536];  // X tile [128 p][256 c] fp16, swz ((p&7)<<4)

  const int srcn = (pr == 1 ? 4 : 0) + n;
  const char* src = (const char*)(xt + ((size_t)srcn * 4096 + p0) * 256);
#pragma unroll
  for (int ps = 0; ps < 16; ++ps) {
    int L = ps * 4096 + tid * 16;
    int row = L >> 9, col = L & 511;
    __builtin_amdgcn_global_load_lds((as1_u32*)(src + (size_t)row * 512 + (col ^ ((row & 7) << 4))),
                                     (as3_u32*)(sB + L), 16, 0, 0);
  }
  const _Float16* wp = w16 + pr * 32768;
  const float* bp = pr == 0 ? tb : (pr == 1 ? pb : gb);

  if (pr == 2) {
    const int o0 = wv * 32;
    f16x8 a[2][8];
#pragma unroll
    for (int mf = 0; mf < 2; ++mf)
#pragma unroll
      for (int kc = 0; kc < 8; ++kc)
        a[mf][kc] = *(const f16x8*)(wp + (size_t)(o0 + mf * 16 + lr) * 256 + kc * 32 + lg * 8);
    __syncthreads();
    f32x4 acc[2][8];
#pragma unroll
    for (int mf = 0; mf < 2; ++mf)
#pragma unroll
      for (int nf = 0; nf < 8; ++nf) acc[mf][nf] = f32x4{0.f, 0.f, 0.f, 0.f};
#pragma unroll
    for (int kc = 0; kc < 8; ++kc) {
      f16x8 bf[8];
#pragma unroll
      for (int nf = 0; nf < 8; ++nf)
        bf[nf] = *(const f16x8*)(sB + (nf * 16 + lr) * 512 + ((kc * 64 + lg * 16) ^ ((lr & 7) << 4)));
#pragma unroll
      for (int mf = 0; mf < 2; ++mf)
#pragma unroll
        for (int nf = 0; nf < 8; ++nf)
          acc[mf][nf] = __builtin_amdgcn_mfma_f32_16x16x32_f16(a[mf][kc], bf[nf], acc[mf][nf], 0, 0, 0);
    }
    // g blocked: [pblk=p>>5][ci][p&31], per n
    _Float16* out = g16 + (size_t)n * 524288;
#pragma unroll
    for (int mf = 0; mf < 2; ++mf)
#pragma unroll
      for (int r = 0; r < 4; ++r) {
        int o = o0 + mf * 16 + lg * 4 + r;
        float bias = bp[o];
#pragma unroll
        for (int nf = 0; nf < 8; ++nf) {
          int pp = p0 + nf * 16 + lr;
          out[(size_t)((pp >> 5) * 128 + o) * 32 + (pp & 31)] = (_Float16)(acc[mf][nf][r] + bias);
        }
      }
  } else {
    __syncthreads();
    const int pw0 = wv * 32;
    f32x4 acc[2][8];
#pragma unroll
    for (int mf = 0; mf < 2; ++mf)
#pragma unroll
      for (int nf = 0; nf < 8; ++nf) acc[mf][nf] = f32x4{0.f, 0.f, 0.f, 0.f};
#pragma unroll 2
    for (int kc = 0; kc < 8; ++kc) {
      f16x8 bf[8];
#pragma unroll
      for (int nf = 0; nf < 8; ++nf)
        bf[nf] = *(const f16x8*)(wp + (size_t)(nf * 16 + lr) * 256 + kc * 32 + lg * 8);
      f16x8 af[2];
#pragma unroll
      for (int mf = 0; mf < 2; ++mf)
        af[mf] = *(const f16x8*)(sB + (pw0 + mf * 16 + lr) * 512 + ((kc * 64 + lg * 16) ^ ((lr & 7) << 4)));
#pragma unroll
      for (int mf = 0; mf < 2; ++mf)
#pragma unroll
        for (int nf = 0; nf < 8; ++nf)
          acc[mf][nf] = __builtin_amdgcn_mfma_f32_16x16x32_f16(af[mf], bf[nf], acc[mf][nf], 0, 0, 0);
    }
    _Float16* out = (pr == 0 ? th16 : ph16) + (size_t)n * 4096 * 128;
#pragma unroll
    for (int mf = 0; mf < 2; ++mf)
#pragma unroll
      for (int r = 0; r < 4; ++r) {
        int p = p0 + pw0 + mf * 16 + lg * 4 + r;
#pragma unroll
        for (int nf = 0; nf < 8; ++nf) {
          int o = nf * 16 + lr;
          out[(size_t)p * 128 + o] = (_Float16)(acc[mf][nf][r] + bp[o]);
        }
      }
  }
}

// ---------------- flash attention: 1024 blocks (4/CU, 16 waves/CU), 4 waves x 32q
// (2 qg), KVBLK=32, each block owns one KV EIGHTH (512 kpos, 16 iters).
// r12-proven inner tile; fp16 partials + 8-way merge.
__global__ __launch_bounds__(256, 4) void attn_kernel(
    const _Float16* __restrict__ th16, const _Float16* __restrict__ ph16,
    const _Float16* __restrict__ g16, _Float16* __restrict__ po_lo,
    _Float16* __restrict__ po_hi, float2* __restrict__ ml) {
  const int lin = blockIdx.x;  // 1024
  const int xcd = lin & 7;     // (n, kv-half) per XCD -> ~1MB K/G L2-resident
  const int n = xcd >> 1;
  const int kvhh = xcd & 1;
  const int rest = lin >> 3;   // 0..127
  const int qt = rest >> 2;    // 0..31
  const int kv8 = kvhh * 4 + (rest & 3);  // 0..7
  const int q0 = qt * 128;
  const int tid = threadIdx.x;
  const int wv = tid >> 6, lane = tid & 63, lg = lane >> 4, lr = lane & 15;
  const int kv0 = kv8 * 512;

  // K dbuf 2x8KB @0 | G dbuf 2x8KB @16384 | P 4wv x 2qg x 1KB @32768  (=40KB, 4/CU)
  __shared__ __align__(16) char smem[40960];
#define KBUF(B) (smem + (B) * 8192)
#define GBUF(B) (smem + 16384 + (B) * 8192)
  char* pB = smem + 32768 + wv * 2048;

  const _Float16* thn = th16 + (size_t)n * 4096 * 128;             // [p][ci]
  const char* phn = (const char*)(ph16 + (size_t)n * 4096 * 128);  // [p][ci]
  const char* ggn = (const char*)(g16 + (size_t)n * 524288);       // blocked [128][128][32]

  // pre-swizzled staging sources (linear LDS dest + inverse-swz source + swz reads)
  // K: 32 rows x 256B, swz (row&7)<<4 ; G: 128 rows x 64B, swz ((row>>1)&3)<<4
  const char* ksrc = phn + (size_t)kv0 * 256 + (tid >> 4) * 256 +
                     (((tid & 15) * 16) ^ (((tid >> 4) & 7) << 4));
  const char* gsrc = ggn + (size_t)kv8 * 131072 + (tid >> 2) * 64 +
                     (((tid & 3) * 16) ^ (((tid >> 3) & 3) << 4));

#define STAGE(KT, B)                                                                     \
  do {                                                                                   \
    const char* ks = ksrc + (size_t)(KT) * 8192;                                         \
    const char* gs = gsrc + (size_t)(KT) * 8192;                                         \
    char* kd = KBUF(B) + tid * 16;                                                       \
    char* gd = GBUF(B) + tid * 16;                                                       \
    __builtin_amdgcn_global_load_lds((as1_u32*)ks, (as3_u32*)kd, 16, 0, 0);              \
    __builtin_amdgcn_global_load_lds((as1_u32*)(ks + 4096), (as3_u32*)(kd + 4096), 16, 0, 0); \
    __builtin_amdgcn_global_load_lds((as1_u32*)gs, (as3_u32*)gd, 16, 0, 0);              \
    __builtin_amdgcn_global_load_lds((as1_u32*)(gs + 4096), (as3_u32*)(gd + 4096), 16, 0, 0); \
  } while (0)

  // Q fragments (B-operand): B[k=ci][q=lr] per qg, vector loads from [p][ci]
  f16x8 qf[2][4];
#pragma unroll
  for (int qg = 0; qg < 2; ++qg)
#pragma unroll
    for (int ch = 0; ch < 4; ++ch)
      qf[qg][ch] = *(const f16x8*)(thn + (size_t)(q0 + wv * 32 + qg * 16 + lr) * 128 +
                                   ch * 32 + lg * 8);

  const int swzk = (lr & 7) << 4;         // K 256B rows
  const int swzg = ((lr >> 1) & 3) << 4;  // G 64B rows (balanced)
  const int swzp = ((lr >> 1) & 3) << 4;  // P 64B rows (balanced)

  f32x4 acc[2][8];
#pragma unroll
  for (int qg = 0; qg < 2; ++qg)
#pragma unroll
    for (int of = 0; of < 8; ++of) acc[qg][of] = f32x4{0.f, 0.f, 0.f, 0.f};
  float m[2] = {-INFINITY, -INFINITY};
  float lrow[2] = {0.f, 0.f};  // lane-partial; summed across lg at epilogue

  STAGE(0, 0);
  asm volatile("s_waitcnt vmcnt(0)" ::: "memory");
  __syncthreads();

  for (int kt = 0; kt < 16; ++kt) {
    const int b = kt & 1;
    // issue next tile FIRST, then counted wait: only STAGE(kt) must have landed.
    if (kt < 15) {
      STAGE(kt + 1, b ^ 1);
      asm volatile("s_waitcnt vmcnt(4)" ::: "memory");
    } else {
      asm volatile("s_waitcnt vmcnt(0)" ::: "memory");
    }
    __builtin_amdgcn_sched_barrier(0);

    // QK: S^T[k=cf*16+lg*4+r][q=lr] per qg; each K frag feeds both qg
    const char* kb = KBUF(b);
    f32x4 s[2][2];
#pragma unroll
    for (int cf = 0; cf < 2; ++cf) {
      s[cf][0] = f32x4{0.f, 0.f, 0.f, 0.f};
      s[cf][1] = f32x4{0.f, 0.f, 0.f, 0.f};
    }
    __builtin_amdgcn_s_setprio(1);
#pragma unroll
    for (int cf = 0; cf < 2; ++cf) {
      const char* krow = kb + (cf * 16 + lr) * 256;
#pragma unroll
      for (int ch = 0; ch < 4; ++ch) {
        f16x8 kf = *(const f16x8*)(krow + ((ch * 64 + lg * 16) ^ swzk));
        s[cf][0] = __builtin_amdgcn_mfma_f32_16x16x32_f16(kf, qf[0][ch], s[cf][0], 0, 0, 0);
        s[cf][1] = __builtin_amdgcn_mfma_f32_16x16x32_f16(kf, qf[1][ch], s[cf][1], 0, 0, 0);
      }
    }
    __builtin_amdgcn_s_setprio(0);

    // lane-local max per qg; cross-lane reduce only when the __all gate fails
    float mt0 = fmaxf(fmaxf(fmaxf(s[0][0][0], s[0][0][1]), fmaxf(s[0][0][2], s[0][0][3])),
                      fmaxf(fmaxf(s[1][0][0], s[1][0][1]), fmaxf(s[1][0][2], s[1][0][3])));
    float mt1 = fmaxf(fmaxf(fmaxf(s[0][1][0], s[0][1][1]), fmaxf(s[0][1][2], s[0][1][3])),
                      fmaxf(fmaxf(s[1][1][0], s[1][1][1]), fmaxf(s[1][1][2], s[1][1][3])));
    bool ok = (mt0 <= m[0] + 8.0f) && (mt1 <= m[1] + 8.0f);
    if (!__all(ok)) {
      // group max over the 4 lanes sharing q (lg dimension)
      mt0 = fmaxf(mt0, __shfl_xor(mt0, 16)); mt0 = fmaxf(mt0, __shfl_xor(mt0, 32));
      mt1 = fmaxf(mt1, __shfl_xor(mt1, 16)); mt1 = fmaxf(mt1, __shfl_xor(mt1, 32));
      float mn0 = fmaxf(m[0], mt0), mn1 = fmaxf(m[1], mt1);
      float sc0 = __expf(m[0] - mn0), sc1 = __expf(m[1] - mn1);
#pragma unroll
      for (int of = 0; of < 8; ++of) { acc[0][of] *= sc0; acc[1][of] *= sc1; }
      lrow[0] *= sc0; lrow[1] *= sc1;
      m[0] = mn0; m[1] = mn1;
    }
#pragma unroll
    for (int qg = 0; qg < 2; ++qg) {
      char* prow = pB + qg * 1024 + lr * 64;
      float psum = 0.f;
#pragma unroll
      for (int cf = 0; cf < 2; ++cf) {
        float p0 = __expf(s[cf][qg][0] - m[qg]);
        float p1 = __expf(s[cf][qg][1] - m[qg]);
        float p2 = __expf(s[cf][qg][2] - m[qg]);
        float p3 = __expf(s[cf][qg][3] - m[qg]);
        psum += (p0 + p1) + (p2 + p3);
        unsigned long long w = (unsigned long long)packh2(p0, p1) |
                               ((unsigned long long)packh2(p2, p3) << 32);
        *(unsigned long long*)(prow + ((cf * 32 + lg * 8) ^ swzp)) = w;
      }
      lrow[qg] += psum;  // lane-partial; no shfl here
    }

    // PV: O^T[ci][q] += G * P^T per qg; each G frag feeds both qg
    const char* gb = GBUF(b);
    f16x8 pf0 = *(const f16x8*)(pB + lr * 64 + ((lg * 16) ^ swzp));
    f16x8 pf1 = *(const f16x8*)(pB + 1024 + lr * 64 + ((lg * 16) ^ swzp));
    __builtin_amdgcn_s_setprio(1);
#pragma unroll
    for (int of = 0; of < 8; ++of) {
      f16x8 gf = *(const f16x8*)(gb + (of * 16 + lr) * 64 + ((lg * 16) ^ swzg));
      acc[0][of] = __builtin_amdgcn_mfma_f32_16x16x32_f16(gf, pf0, acc[0][of], 0, 0, 0);
      acc[1][of] = __builtin_amdgcn_mfma_f32_16x16x32_f16(gf, pf1, acc[1][of], 0, 0, 0);
    }
    __builtin_amdgcn_s_setprio(0);
    __builtin_amdgcn_s_barrier();  // raw barrier; staging loads stay in flight
  }

  // finalize l: sum lane-partials across the 4 lanes sharing each q
  float L0 = lrow[0];
  L0 += __shfl_xor(L0, 16); L0 += __shfl_xor(L0, 32);
  float L1 = lrow[1];
  L1 += __shfl_xor(L1, 16); L1 += __shfl_xor(L1, 32);

  // epilogue: drain everything, then reuse smem for the transpose
  asm volatile("s_waitcnt vmcnt(0)" ::: "memory");
  __syncthreads();
  _Float16* pobase = (kv8 < 4 ? po_lo : po_hi);
  const int slot = (kv8 & 3) * 4 + n;
  float* ep = (float*)(smem + wv * 8448);  // 16 rows x 132 f32, per wave
#pragma unroll
  for (int qg = 0; qg < 2; ++qg) {
#pragma unroll
    for (int of = 0; of < 8; ++of)
#pragma unroll
      for (int r = 0; r < 4; ++r) ep[lr * 132 + of * 16 + lg * 4 + r] = acc[qg][of][r];
    char* pon = (char*)(pobase + ((size_t)slot * 4096 + q0 + wv * 32 + qg * 16) * 128);
#pragma unroll
    for (int it = 0; it < 4; ++it) {
      int e = lane + it * 64;
      int qq = e >> 4, c8 = e & 15;
      f32x4 va = *(const f32x4*)(ep + qq * 132 + c8 * 8);
      f32x4 vb = *(const f32x4*)(ep + qq * 132 + c8 * 8 + 4);
      f16x8 h;
#pragma unroll
      for (int j = 0; j < 4; ++j) { h[j] = (_Float16)va[j]; h[4 + j] = (_Float16)vb[j]; }
      *(f16x8*)(pon + (size_t)qq * 256 + c8 * 16) = h;
    }
    if (lg == 0)
      ml[(size_t)(kv8 * 4 + n) * 4096 + q0 + wv * 32 + qg * 16 + lr] =
          float2{m[qg], qg == 0 ? L0 : L1};
  }
#undef STAGE
#undef KBUF
#undef GBUF
}

// ---------------- merge the eight KV slices -> o16 fp16 [n][q][ci]
__global__ __launch_bounds__(256) void merge_kernel(const _Float16* __restrict__ po_lo,
                                                    const _Float16* __restrict__ po_hi,
                                                    const float2* __restrict__ ml,
                                                    _Float16* __restrict__ o16) {
  const int t = threadIdx.x;
  const int row = blockIdx.x * 32 + (t >> 3);  // 0..16383 = n*4096+q
  const int c0 = (t & 7) * 16;
  float2 v[8];
  float M = -INFINITY;
#pragma unroll
  for (int k = 0; k < 8; ++k) {
    v[k] = ml[(size_t)k * 16384 + row];
    M = fmaxf(M, v[k].x);
  }
  float f[8], L = 0.f;
#pragma unroll
  for (int k = 0; k < 8; ++k) {
    f[k] = __expf(v[k].x - M);
    L += v[k].y * f[k];
  }
  const float inv = 1.0f / L;
  float o[16];
#pragma unroll
  for (int j = 0; j < 16; ++j) o[j] = 0.f;
#pragma unroll
  for (int k = 0; k < 8; ++k) {
    const _Float16* base = (k < 4 ? po_lo : po_hi);
    const _Float16* p = base + ((size_t)(k & 3) * 16384 + row) * 128 + c0;
    f16x8 a = *(const f16x8*)p;
    f16x8 b = *(const f16x8*)(p + 8);
#pragma unroll
    for (int j = 0; j < 8; ++j) {
      o[j] += f[k] * (float)a[j];
      o[8 + j] += f[k] * (float)b[j];
    }
  }
  f16x8 h0, h1;
#pragma unroll
  for (int j = 0; j < 8; ++j) {
    h0[j] = (_Float16)(o[j] * inv);
    h1[j] = (_Float16)(o[8 + j] * inv);
  }
  _Float16* out = o16 + (size_t)row * 128 + c0;
  *(f16x8*)out = h0;
  *(f16x8*)(out + 8) = h1;
}

// ---------------- rec projection (MFMA) -> fp16 + per-block BN partial stats
__global__ __launch_bounds__(256) void rec_kernel(
    const _Float16* __restrict__ o16, const _Float16* __restrict__ rw16,
    const float* __restrict__ rb, _Float16* __restrict__ rec16,
    float* __restrict__ partial) {
  const int pblk = blockIdx.x;  // 128 tiles of 32 positions
  const int n = blockIdx.y;
  const int p0 = pblk * 32;
  const int blin = n * 128 + pblk;  // 0..511
  const int tid = threadIdx.x, wv = tid >> 6, lane = tid & 63, lg = lane >> 4, lr = lane & 15;
  __shared__ __align__(16) char sB[8192];  // O tile [32 pos][128 ci] fp16, swizzled
  const char* o16n = (const char*)(o16 + (size_t)n * 4096 * 128);
  const char* srcb = o16n + (size_t)p0 * 256 + (tid >> 4) * 256 +
                     (((tid & 15) * 16) ^ (((tid >> 4) & 7) << 4));
  __builtin_amdgcn_global_load_lds((as1_u32*)srcb, (as3_u32*)(sB + tid * 16), 16, 0, 0);
  __builtin_amdgcn_global_load_lds((as1_u32*)(srcb + 4096), (as3_u32*)(sB + 4096 + tid * 16), 16, 0, 0);

  const int wc0 = wv * 64;
  f16x8 a[4][4];
#pragma unroll
  for (int mf = 0; mf < 4; ++mf)
#pragma unroll
    for (int kc = 0; kc < 4; ++kc)
      a[mf][kc] = *(const f16x8*)(rw16 + (size_t)(wc0 + mf * 16 + lr) * 128 + kc * 32 + lg * 8);
  __syncthreads();

  f32x4 acc[4][2];
#pragma unroll
  for (int mf = 0; mf < 4; ++mf) {
    acc[mf][0] = f32x4{0.f, 0.f, 0.f, 0.f};
    acc[mf][1] = f32x4{0.f, 0.f, 0.f, 0.f};
  }
  const int xorv = (lr & 7) << 4;
#pragma unroll
  for (int kc = 0; kc < 4; ++kc) {
    int cb = (kc * 64 + lg * 16) ^ xorv;
    f16x8 b0 = *(const f16x8*)(sB + lr * 256 + cb);
    f16x8 b1 = *(const f16x8*)(sB + (16 + lr) * 256 + cb);
#pragma unroll
    for (int mf = 0; mf < 4; ++mf) {
      acc[mf][0] = __builtin_amdgcn_mfma_f32_16x16x32_f16(a[mf][kc], b0, acc[mf][0], 0, 0, 0);
      acc[mf][1] = __builtin_amdgcn_mfma_f32_16x16x32_f16(a[mf][kc], b1, acc[mf][1], 0, 0, 0);
    }
  }
  float* pslot = partial + (size_t)blin * 512;
#pragma unroll
  for (int mf = 0; mf < 4; ++mf)
#pragma unroll
    for (int r = 0; r < 4; ++r) {
      int c = wc0 + mf * 16 + lg * 4 + r;
      float bias = rb[c];
      float v0 = acc[mf][0][r] + bias;
      float v1 = acc[mf][1][r] + bias;
      rec16[((size_t)n * 256 + c) * 4096 + p0 + lr] = (_Float16)v0;
      rec16[((size_t)n * 256 + c) * 4096 + p0 + 16 + lr] = (_Float16)v1;
      float s = v0 + v1, qd = v0 * v0 + v1 * v1;
      s += __shfl_xor(s, 1); qd += __shfl_xor(qd, 1);
      s += __shfl_xor(s, 2); qd += __shfl_xor(qd, 2);
      s += __shfl_xor(s, 4); qd += __shfl_xor(qd, 4);
      s += __shfl_xor(s, 8); qd += __shfl_xor(qd, 8);
      if (lr == 0) {
        pslot[c] = s;
        pslot[256 + c] = qd;
      }
    }
}

// ---------------- reduce per-block partials -> stats[512]
__global__ __launch_bounds__(256) void stats_reduce(const float* __restrict__ partial,
                                                    float* __restrict__ stats) {
  const int j = blockIdx.x * 256 + threadIdx.x;  // 0..511
  float s = 0.f;
#pragma unroll 8
  for (int b = 0; b < 512; ++b) s += partial[(size_t)b * 512 + j];
  stats[j] = s;
}

// ---------------- BN apply + residual (reads fp16 rec result)
__global__ __launch_bounds__(256) void bn_kernel(
    const float* __restrict__ x, const float* __restrict__ gamma,
    const float* __restrict__ beta, const float* __restrict__ stats,
    const _Float16* __restrict__ rec16, float* __restrict__ out) {
  const size_t i4 = (size_t)blockIdx.x * 256 + threadIdx.x;
  const int c = (int)((i4 >> 10) & 255);
  const float inv = 1.f / 16384.f;
  const float mean = stats[c] * inv;
  const float var = stats[256 + c] * inv - mean * mean;
  const float gm = gamma[c] * rsqrtf(var + EPSV);
  const float bt = beta[c];
  f16x4 r4 = ((const f16x4*)rec16)[i4];
  float4 xv = ((const float4*)x)[i4];
  float4 o;
  o.x = xv.x + ((float)r4[0] - mean) * gm + bt;
  o.y = xv.y + ((float)r4[1] - mean) * gm + bt;
  o.z = xv.z + ((float)r4[2] - mean) * gm + bt;
  o.w = xv.w + ((float)r4[3] - mean) * gm + bt;
  ((float4*)out)[i4] = o;
}

extern "C" void kernel_launch(void* const* d_in, const int* in_sizes, int n_in,
                              void* d_out, int out_size, void* d_ws, size_t ws_size,
                              hipStream_t stream) {
  const float* x  = (const float*)d_in[0];
  const float* y  = (const float*)d_in[1];
  const float* tw = (const float*)d_in[2];
  const float* tb = (const float*)d_in[3];
  const float* pw = (const float*)d_in[4];
  const float* pb = (const float*)d_in[5];
  const float* gw = (const float*)d_in[6];
  const float* gb = (const float*)d_in[7];
  const float* rw = (const float*)d_in[8];
  const float* rb = (const float*)d_in[9];
  const float* gamma = (const float*)d_in[10];
  const float* beta  = (const float*)d_in[11];
  float* out = (float*)d_out;
  _Float16* xt    = (_Float16*)d_ws;        // 16MB [2][4][4096][256]; dead after proj
  _Float16* w16   = xt + 8388608;           // 256KB [4][32768]
  _Float16* th16  = w16 + 131072;           // 4MB [n][p][ci]
  _Float16* ph16  = th16 + 2097152;         // 4MB [n][p][ci]
  _Float16* g16   = ph16 + 2097152;         // 4MB [n] blocked [128][128][32]
  _Float16* o16   = g16 + 2097152;          // 4MB [n][q][ci]
  _Float16* rec16 = o16 + 2097152;          // 8MB [n][c][p]
  float* partial  = (float*)(rec16 + 4194304);  // 1MB [512][512]
  float* stats    = partial + 262144;           // 512 f32
  float2* ml      = (float2*)(stats + 512);     // 1MB [8][4][4096]
  _Float16* po_hi = (_Float16*)(ml + 131072);   // 16MB kv8 4..7
  _Float16* po_lo = xt;                         // 16MB kv8 0..3 (aliases dead xt)
  _Float16* rw16 = w16 + 98304;
  pack_w<<<dim3(512), 256, 0, stream>>>(tw, pw, gw, rw, w16);
  pack_xy<<<dim3(512, 4, 2), 256, 0, stream>>>(x, y, xt);
  proj_kernel<<<dim3(32, 12), 256, 0, stream>>>(xt, w16, tb, pb, gb, th16, ph16, g16);
  attn_kernel<<<dim3(1024), 256, 0, stream>>>(th16, ph16, g16, po_lo, po_hi, ml);
  merge_kernel<<<dim3(512), 256, 0, stream>>>(po_lo, po_hi, ml, o16);
  rec_kernel<<<dim3(128, 4), 256, 0, stream>>>(o16, rw16, rb, rec16, partial);
  stats_reduce<<<dim3(2), 256, 0, stream>>>(partial, stats);
  bn_kernel<<<dim3(4096), 256, 0, stream>>>(x, gamma, beta, stats, rec16, out);
}

// Round 15
// 130.102 us; speedup vs baseline: 1.2278x; 1.2278x over previous
//
#include <hip/hip_runtime.h>
#include <math.h>

#define EPSV 1e-5f

typedef __attribute__((ext_vector_type(8))) _Float16 f16x8;
typedef __attribute__((ext_vector_type(4))) _Float16 f16x4;
typedef __attribute__((ext_vector_type(4))) float f32x4;

typedef __attribute__((address_space(1))) const unsigned int as1_u32;
typedef __attribute__((address_space(3))) unsigned int as3_u32;

static __device__ __forceinline__ unsigned packh2(float a, float b) {
  auto v = __builtin_amdgcn_cvt_pkrtz(a, b);  // __fp16 ext_vector(2)
  return __builtin_bit_cast(unsigned, v);
}

// ---------------- pack weights fp32 -> fp16 [4][*] (tw,pw,gw: 128x256; rw: 256x128)
__global__ __launch_bounds__(256) void pack_w(const float* __restrict__ tw,
                                              const float* __restrict__ pw,
                                              const float* __restrict__ gw,
                                              const float* __restrict__ rw,
                                              _Float16* __restrict__ w16) {
  int i = blockIdx.x * 256 + threadIdx.x;  // 131072
  const float* s = i < 32768 ? tw : (i < 65536 ? pw : (i < 98304 ? gw : rw));
  w16[i] = (_Float16)s[i & 32767];
}

// ---------------- pack x,y fp32 [n][c][p] -> fp16 transposed [src][n][p][c]
__global__ __launch_bounds__(256) void pack_xy(const float* __restrict__ x,
                                               const float* __restrict__ y,
                                               _Float16* __restrict__ xt) {
  const int n = blockIdx.y, s = blockIdx.z;
  const int g = blockIdx.x * 256 + threadIdx.x;  // 131072 per (n,s)
  const int p = g & 4095, c8 = g >> 12;          // c8 0..31
  const float* src = (s ? y : x) + ((size_t)n * 256 + c8 * 8) * 4096 + p;
  f16x8 v;
#pragma unroll
  for (int j = 0; j < 8; ++j) v[j] = (_Float16)src[(size_t)j * 4096];
  *(f16x8*)(xt + ((size_t)(s * 4 + n) * 4096 + p) * 256 + c8 * 8) = v;
}

// ---------------- projections via MFMA.
// pr 0 (theta): -> [p][ci]; pr 1 (phi): -> [p][ci]; pr 2 (g): -> blocked [p/32][ci][32]
__global__ __launch_bounds__(256) void proj_kernel(
    const _Float16* __restrict__ xt, const _Float16* __restrict__ w16,
    const float* __restrict__ tb, const float* __restrict__ pb,
    const float* __restrict__ gb, _Float16* __restrict__ th16,
    _Float16* __restrict__ ph16, _Float16* __restrict__ g16) {
  const int ptile = blockIdx.x;  // 32 tiles of 128 positions
  const int z = blockIdx.y;      // 12 = 3 pr * 4 n
  const int pr = z >> 2, n = z & 3;
  const int p0 = ptile * 128;
  const int tid = threadIdx.x, wv = tid >> 6, lane = tid & 63, lg = lane >> 4, lr = lane & 15;

  __shared__ __align__(16) char sB[65536];  // X tile [128 p][256 c] fp16, swz ((p&7)<<4)

  const int srcn = (pr == 1 ? 4 : 0) + n;
  const char* src = (const char*)(xt + ((size_t)srcn * 4096 + p0) * 256);
#pragma unroll
  for (int ps = 0; ps < 16; ++ps) {
    int L = ps * 4096 + tid * 16;
    int row = L >> 9, col = L & 511;
    __builtin_amdgcn_global_load_lds((as1_u32*)(src + (size_t)row * 512 + (col ^ ((row & 7) << 4))),
                                     (as3_u32*)(sB + L), 16, 0, 0);
  }
  const _Float16* wp = w16 + pr * 32768;
  const float* bp = pr == 0 ? tb : (pr == 1 ? pb : gb);

  if (pr == 2) {
    const int o0 = wv * 32;
    f16x8 a[2][8];
#pragma unroll
    for (int mf = 0; mf < 2; ++mf)
#pragma unroll
      for (int kc = 0; kc < 8; ++kc)
        a[mf][kc] = *(const f16x8*)(wp + (size_t)(o0 + mf * 16 + lr) * 256 + kc * 32 + lg * 8);
    __syncthreads();
    f32x4 acc[2][8];
#pragma unroll
    for (int mf = 0; mf < 2; ++mf)
#pragma unroll
      for (int nf = 0; nf < 8; ++nf) acc[mf][nf] = f32x4{0.f, 0.f, 0.f, 0.f};
#pragma unroll
    for (int kc = 0; kc < 8; ++kc) {
      f16x8 bf[8];
#pragma unroll
      for (int nf = 0; nf < 8; ++nf)
        bf[nf] = *(const f16x8*)(sB + (nf * 16 + lr) * 512 + ((kc * 64 + lg * 16) ^ ((lr & 7) << 4)));
#pragma unroll
      for (int mf = 0; mf < 2; ++mf)
#pragma unroll
        for (int nf = 0; nf < 8; ++nf)
          acc[mf][nf] = __builtin_amdgcn_mfma_f32_16x16x32_f16(a[mf][kc], bf[nf], acc[mf][nf], 0, 0, 0);
    }
    // g blocked: [pblk=p>>5][ci][p&31], per n
    _Float16* out = g16 + (size_t)n * 524288;
#pragma unroll
    for (int mf = 0; mf < 2; ++mf)
#pragma unroll
      for (int r = 0; r < 4; ++r) {
        int o = o0 + mf * 16 + lg * 4 + r;
        float bias = bp[o];
#pragma unroll
        for (int nf = 0; nf < 8; ++nf) {
          int pp = p0 + nf * 16 + lr;
          out[(size_t)((pp >> 5) * 128 + o) * 32 + (pp & 31)] = (_Float16)(acc[mf][nf][r] + bias);
        }
      }
  } else {
    __syncthreads();
    const int pw0 = wv * 32;
    f32x4 acc[2][8];
#pragma unroll
    for (int mf = 0; mf < 2; ++mf)
#pragma unroll
      for (int nf = 0; nf < 8; ++nf) acc[mf][nf] = f32x4{0.f, 0.f, 0.f, 0.f};
#pragma unroll 2
    for (int kc = 0; kc < 8; ++kc) {
      f16x8 bf[8];
#pragma unroll
      for (int nf = 0; nf < 8; ++nf)
        bf[nf] = *(const f16x8*)(wp + (size_t)(nf * 16 + lr) * 256 + kc * 32 + lg * 8);
      f16x8 af[2];
#pragma unroll
      for (int mf = 0; mf < 2; ++mf)
        af[mf] = *(const f16x8*)(sB + (pw0 + mf * 16 + lr) * 512 + ((kc * 64 + lg * 16) ^ ((lr & 7) << 4)));
#pragma unroll
      for (int mf = 0; mf < 2; ++mf)
#pragma unroll
        for (int nf = 0; nf < 8; ++nf)
          acc[mf][nf] = __builtin_amdgcn_mfma_f32_16x16x32_f16(af[mf], bf[nf], acc[mf][nf], 0, 0, 0);
    }
    _Float16* out = (pr == 0 ? th16 : ph16) + (size_t)n * 4096 * 128;
#pragma unroll
    for (int mf = 0; mf < 2; ++mf)
#pragma unroll
      for (int r = 0; r < 4; ++r) {
        int p = p0 + pw0 + mf * 16 + lg * 4 + r;
#pragma unroll
        for (int nf = 0; nf < 8; ++nf) {
          int o = nf * 16 + lr;
          out[(size_t)p * 128 + o] = (_Float16)(acc[mf][nf][r] + bp[o]);
        }
      }
  }
}

// ---------------- flash attention: 512 blocks, 4 waves x 32q (2 qg), KVBLK=32,
// each block owns one KV quarter (1024 kpos, 32 iters). r12-proven structure.
__global__ __launch_bounds__(256, 2) void attn_kernel(
    const _Float16* __restrict__ th16, const _Float16* __restrict__ ph16,
    const _Float16* __restrict__ g16, _Float16* __restrict__ po16,
    float2* __restrict__ ml) {
  const int lin = blockIdx.x;  // 512
  const int xcd = lin & 7;     // (n,kv-half) per XCD -> K/G slices L2-resident
  const int n = xcd >> 1;
  const int kvh = xcd & 1;
  const int rest = lin >> 3;   // 0..63
  const int qt = rest >> 1;    // 0..31
  const int kvq = kvh * 2 + (rest & 1);
  const int q0 = qt * 128;
  const int tid = threadIdx.x;
  const int wv = tid >> 6, lane = tid & 63, lg = lane >> 4, lr = lane & 15;
  const int kv0 = kvq * 1024;

  // K dbuf 2x8KB @0 | G dbuf 2x8KB @16384 | P 4wv x 2qg x 1KB @32768  (=40KB)
  __shared__ __align__(16) char smem[40960];
#define KBUF(B) (smem + (B) * 8192)
#define GBUF(B) (smem + 16384 + (B) * 8192)
  char* pB = smem + 32768 + wv * 2048;

  const _Float16* thn = th16 + (size_t)n * 4096 * 128;             // [p][ci]
  const char* phn = (const char*)(ph16 + (size_t)n * 4096 * 128);  // [p][ci]
  const char* ggn = (const char*)(g16 + (size_t)n * 524288);       // blocked [128][128][32]

  // pre-swizzled staging sources (linear LDS dest + inverse-swz source + swz reads)
  // K: 32 rows x 256B, swz (row&7)<<4 ; G: 128 rows x 64B, swz ((row>>1)&3)<<4
  const char* ksrc = phn + (size_t)kv0 * 256 + (tid >> 4) * 256 +
                     (((tid & 15) * 16) ^ (((tid >> 4) & 7) << 4));
  const char* gsrc = ggn + (size_t)kvq * 262144 + (tid >> 2) * 64 +
                     (((tid & 3) * 16) ^ (((tid >> 3) & 3) << 4));

#define STAGE(KT, B)                                                                     \
  do {                                                                                   \
    const char* ks = ksrc + (size_t)(KT) * 8192;                                         \
    const char* gs = gsrc + (size_t)(KT) * 8192;                                         \
    char* kd = KBUF(B) + tid * 16;                                                       \
    char* gd = GBUF(B) + tid * 16;                                                       \
    __builtin_amdgcn_global_load_lds((as1_u32*)ks, (as3_u32*)kd, 16, 0, 0);              \
    __builtin_amdgcn_global_load_lds((as1_u32*)(ks + 4096), (as3_u32*)(kd + 4096), 16, 0, 0); \
    __builtin_amdgcn_global_load_lds((as1_u32*)gs, (as3_u32*)gd, 16, 0, 0);              \
    __builtin_amdgcn_global_load_lds((as1_u32*)(gs + 4096), (as3_u32*)(gd + 4096), 16, 0, 0); \
  } while (0)

  // Q fragments (B-operand): B[k=ci][q=lr] per qg, vector loads from [p][ci]
  f16x8 qf[2][4];
#pragma unroll
  for (int qg = 0; qg < 2; ++qg)
#pragma unroll
    for (int ch = 0; ch < 4; ++ch)
      qf[qg][ch] = *(const f16x8*)(thn + (size_t)(q0 + wv * 32 + qg * 16 + lr) * 128 +
                                   ch * 32 + lg * 8);

  const int swzk = (lr & 7) << 4;         // K 256B rows
  const int swzg = ((lr >> 1) & 3) << 4;  // G 64B rows (balanced)
  const int swzp = ((lr >> 1) & 3) << 4;  // P 64B rows (balanced)

  f32x4 acc[2][8];
#pragma unroll
  for (int qg = 0; qg < 2; ++qg)
#pragma unroll
    for (int of = 0; of < 8; ++of) acc[qg][of] = f32x4{0.f, 0.f, 0.f, 0.f};
  float m[2] = {-INFINITY, -INFINITY};
  float lrow[2] = {0.f, 0.f};  // lane-partial; summed across lg at epilogue

  STAGE(0, 0);
  __syncthreads();

  for (int kt = 0; kt < 32; ++kt) {
    const int b = kt & 1;
    if (kt < 31) STAGE(kt + 1, b ^ 1);

    // QK: S^T[k=cf*16+lg*4+r][q=lr] per qg; each K frag feeds both qg
    const char* kb = KBUF(b);
    f32x4 s[2][2];
#pragma unroll
    for (int cf = 0; cf < 2; ++cf) {
      s[cf][0] = f32x4{0.f, 0.f, 0.f, 0.f};
      s[cf][1] = f32x4{0.f, 0.f, 0.f, 0.f};
    }
    __builtin_amdgcn_s_setprio(1);
#pragma unroll
    for (int cf = 0; cf < 2; ++cf) {
      const char* krow = kb + (cf * 16 + lr) * 256;
#pragma unroll
      for (int ch = 0; ch < 4; ++ch) {
        f16x8 kf = *(const f16x8*)(krow + ((ch * 64 + lg * 16) ^ swzk));
        s[cf][0] = __builtin_amdgcn_mfma_f32_16x16x32_f16(kf, qf[0][ch], s[cf][0], 0, 0, 0);
        s[cf][1] = __builtin_amdgcn_mfma_f32_16x16x32_f16(kf, qf[1][ch], s[cf][1], 0, 0, 0);
      }
    }
    __builtin_amdgcn_s_setprio(0);

    // lane-local max per qg; cross-lane reduce only when the __all gate fails
    float mt0 = fmaxf(fmaxf(fmaxf(s[0][0][0], s[0][0][1]), fmaxf(s[0][0][2], s[0][0][3])),
                      fmaxf(fmaxf(s[1][0][0], s[1][0][1]), fmaxf(s[1][0][2], s[1][0][3])));
    float mt1 = fmaxf(fmaxf(fmaxf(s[0][1][0], s[0][1][1]), fmaxf(s[0][1][2], s[0][1][3])),
                      fmaxf(fmaxf(s[1][1][0], s[1][1][1]), fmaxf(s[1][1][2], s[1][1][3])));
    bool ok = (mt0 <= m[0] + 8.0f) && (mt1 <= m[1] + 8.0f);
    if (!__all(ok)) {
      // group max over the 4 lanes sharing q (lg dimension)
      mt0 = fmaxf(mt0, __shfl_xor(mt0, 16)); mt0 = fmaxf(mt0, __shfl_xor(mt0, 32));
      mt1 = fmaxf(mt1, __shfl_xor(mt1, 16)); mt1 = fmaxf(mt1, __shfl_xor(mt1, 32));
      float mn0 = fmaxf(m[0], mt0), mn1 = fmaxf(m[1], mt1);
      float sc0 = __expf(m[0] - mn0), sc1 = __expf(m[1] - mn1);
#pragma unroll
      for (int of = 0; of < 8; ++of) { acc[0][of] *= sc0; acc[1][of] *= sc1; }
      lrow[0] *= sc0; lrow[1] *= sc1;
      m[0] = mn0; m[1] = mn1;
    }
#pragma unroll
    for (int qg = 0; qg < 2; ++qg) {
      char* prow = pB + qg * 1024 + lr * 64;
      float psum = 0.f;
#pragma unroll
      for (int cf = 0; cf < 2; ++cf) {
        float p0 = __expf(s[cf][qg][0] - m[qg]);
        float p1 = __expf(s[cf][qg][1] - m[qg]);
        float p2 = __expf(s[cf][qg][2] - m[qg]);
        float p3 = __expf(s[cf][qg][3] - m[qg]);
        psum += (p0 + p1) + (p2 + p3);
        unsigned long long w = (unsigned long long)packh2(p0, p1) |
                               ((unsigned long long)packh2(p2, p3) << 32);
        *(unsigned long long*)(prow + ((cf * 32 + lg * 8) ^ swzp)) = w;
      }
      lrow[qg] += psum;  // lane-partial; no shfl here
    }

    // PV: O^T[ci][q] += G * P^T per qg; each G frag feeds both qg
    const char* gb = GBUF(b);
    f16x8 pf0 = *(const f16x8*)(pB + lr * 64 + ((lg * 16) ^ swzp));
    f16x8 pf1 = *(const f16x8*)(pB + 1024 + lr * 64 + ((lg * 16) ^ swzp));
    __builtin_amdgcn_s_setprio(1);
#pragma unroll
    for (int of = 0; of < 8; ++of) {
      f16x8 gf = *(const f16x8*)(gb + (of * 16 + lr) * 64 + ((lg * 16) ^ swzg));
      acc[0][of] = __builtin_amdgcn_mfma_f32_16x16x32_f16(gf, pf0, acc[0][of], 0, 0, 0);
      acc[1][of] = __builtin_amdgcn_mfma_f32_16x16x32_f16(gf, pf1, acc[1][of], 0, 0, 0);
    }
    __builtin_amdgcn_s_setprio(0);
    __syncthreads();  // drains stage(kt+1); all waves done with buf b
  }

  // finalize l: sum lane-partials across the 4 lanes sharing each q
  float L0 = lrow[0];
  L0 += __shfl_xor(L0, 16); L0 += __shfl_xor(L0, 32);
  float L1 = lrow[1];
  L1 += __shfl_xor(L1, 16); L1 += __shfl_xor(L1, 32);

  // epilogue: transpose O^T -> [q][ci] through LDS; fp16 partial + (m,l)
  float* ep = (float*)(smem + wv * 8448);  // 16 rows x 132 f32, per wave
#pragma unroll
  for (int qg = 0; qg < 2; ++qg) {
#pragma unroll
    for (int of = 0; of < 8; ++of)
#pragma unroll
      for (int r = 0; r < 4; ++r) ep[lr * 132 + of * 16 + lg * 4 + r] = acc[qg][of][r];
    char* pon = (char*)(po16 + ((size_t)(kvq * 4 + n) * 4096 + q0 + wv * 32 + qg * 16) * 128);
#pragma unroll
    for (int it = 0; it < 4; ++it) {
      int e = lane + it * 64;
      int qq = e >> 4, c8 = e & 15;
      f32x4 va = *(const f32x4*)(ep + qq * 132 + c8 * 8);
      f32x4 vb = *(const f32x4*)(ep + qq * 132 + c8 * 8 + 4);
      f16x8 h;
#pragma unroll
      for (int j = 0; j < 4; ++j) { h[j] = (_Float16)va[j]; h[4 + j] = (_Float16)vb[j]; }
      *(f16x8*)(pon + (size_t)qq * 256 + c8 * 16) = h;
    }
    if (lg == 0)
      ml[(size_t)(kvq * 4 + n) * 4096 + q0 + wv * 32 + qg * 16 + lr] =
          float2{m[qg], qg == 0 ? L0 : L1};
  }
#undef STAGE
#undef KBUF
#undef GBUF
}

// ---------------- rec projection (MFMA) with FUSED 4-way merge + BN partial stats
__global__ __launch_bounds__(256) void rec_kernel(
    const _Float16* __restrict__ po16, const float2* __restrict__ ml,
    const _Float16* __restrict__ rw16, const float* __restrict__ rb,
    _Float16* __restrict__ rec16, float* __restrict__ partial) {
  const int pblk = blockIdx.x;  // 128 tiles of 32 positions
  const int n = blockIdx.y;
  const int p0 = pblk * 32;
  const int blin = n * 128 + pblk;  // 0..511
  const int tid = threadIdx.x, wv = tid >> 6, lane = tid & 63, lg = lane >> 4, lr = lane & 15;
  __shared__ __align__(16) char sB[8192];  // merged O tile [32 p][128 ci] fp16, swz ((p&7)<<4)

  // ---- fused merge staging: each thread merges one 16-ci segment of one row
  {
    const int row = tid >> 3;       // p within tile, 0..31
    const int c0 = (tid & 7) * 16;  // ci start
    float2 v[4];
    float M = -INFINITY;
#pragma unroll
    for (int k = 0; k < 4; ++k) {
      v[k] = ml[(size_t)(k * 4 + n) * 4096 + p0 + row];
      M = fmaxf(M, v[k].x);
    }
    float f[4], L = 0.f;
#pragma unroll
    for (int k = 0; k < 4; ++k) {
      f[k] = __expf(v[k].x - M);
      L += v[k].y * f[k];
    }
    const float inv = 1.0f / L;
    float o[16];
#pragma unroll
    for (int j = 0; j < 16; ++j) o[j] = 0.f;
#pragma unroll
    for (int k = 0; k < 4; ++k) {
      const _Float16* p = po16 + ((size_t)(k * 4 + n) * 4096 + p0 + row) * 128 + c0;
      f16x8 a = *(const f16x8*)p;
      f16x8 b = *(const f16x8*)(p + 8);
#pragma unroll
      for (int j = 0; j < 8; ++j) {
        o[j] += f[k] * (float)a[j];
        o[8 + j] += f[k] * (float)b[j];
      }
    }
    f16x8 h0, h1;
#pragma unroll
    for (int j = 0; j < 8; ++j) {
      h0[j] = (_Float16)(o[j] * inv);
      h1[j] = (_Float16)(o[8 + j] * inv);
    }
    char* dst = sB + row * 256;
    const int xr = (row & 7) << 4;
    *(f16x8*)(dst + ((c0 * 2) ^ xr)) = h0;
    *(f16x8*)(dst + ((c0 * 2 + 16) ^ xr)) = h1;
  }

  const int wc0 = wv * 64;
  f16x8 a[4][4];
#pragma unroll
  for (int mf = 0; mf < 4; ++mf)
#pragma unroll
    for (int kc = 0; kc < 4; ++kc)
      a[mf][kc] = *(const f16x8*)(rw16 + (size_t)(wc0 + mf * 16 + lr) * 128 + kc * 32 + lg * 8);
  __syncthreads();

  f32x4 acc[4][2];
#pragma unroll
  for (int mf = 0; mf < 4; ++mf) {
    acc[mf][0] = f32x4{0.f, 0.f, 0.f, 0.f};
    acc[mf][1] = f32x4{0.f, 0.f, 0.f, 0.f};
  }
  const int xorv = (lr & 7) << 4;
#pragma unroll
  for (int kc = 0; kc < 4; ++kc) {
    int cb = (kc * 64 + lg * 16) ^ xorv;
    f16x8 b0 = *(const f16x8*)(sB + lr * 256 + cb);
    f16x8 b1 = *(const f16x8*)(sB + (16 + lr) * 256 + cb);
#pragma unroll
    for (int mf = 0; mf < 4; ++mf) {
      acc[mf][0] = __builtin_amdgcn_mfma_f32_16x16x32_f16(a[mf][kc], b0, acc[mf][0], 0, 0, 0);
      acc[mf][1] = __builtin_amdgcn_mfma_f32_16x16x32_f16(a[mf][kc], b1, acc[mf][1], 0, 0, 0);
    }
  }
  float* pslot = partial + (size_t)blin * 512;
#pragma unroll
  for (int mf = 0; mf < 4; ++mf)
#pragma unroll
    for (int r = 0; r < 4; ++r) {
      int c = wc0 + mf * 16 + lg * 4 + r;
      float bias = rb[c];
      float v0 = acc[mf][0][r] + bias;
      float v1 = acc[mf][1][r] + bias;
      rec16[((size_t)n * 256 + c) * 4096 + p0 + lr] = (_Float16)v0;
      rec16[((size_t)n * 256 + c) * 4096 + p0 + 16 + lr] = (_Float16)v1;
      float s = v0 + v1, qd = v0 * v0 + v1 * v1;
      s += __shfl_xor(s, 1); qd += __shfl_xor(qd, 1);
      s += __shfl_xor(s, 2); qd += __shfl_xor(qd, 2);
      s += __shfl_xor(s, 4); qd += __shfl_xor(qd, 4);
      s += __shfl_xor(s, 8); qd += __shfl_xor(qd, 8);
      if (lr == 0) {
        pslot[c] = s;
        pslot[256 + c] = qd;
      }
    }
}

// ---------------- reduce per-block partials -> stats[512]
__global__ __launch_bounds__(256) void stats_reduce(const float* __restrict__ partial,
                                                    float* __restrict__ stats) {
  const int j = blockIdx.x * 256 + threadIdx.x;  // 0..511
  float s = 0.f;
#pragma unroll 8
  for (int b = 0; b < 512; ++b) s += partial[(size_t)b * 512 + j];
  stats[j] = s;
}

// ---------------- BN apply + residual (reads fp16 rec result)
__global__ __launch_bounds__(256) void bn_kernel(
    const float* __restrict__ x, const float* __restrict__ gamma,
    const float* __restrict__ beta, const float* __restrict__ stats,
    const _Float16* __restrict__ rec16, float* __restrict__ out) {
  const size_t i4 = (size_t)blockIdx.x * 256 + threadIdx.x;
  const int c = (int)((i4 >> 10) & 255);
  const float inv = 1.f / 16384.f;
  const float mean = stats[c] * inv;
  const float var = stats[256 + c] * inv - mean * mean;
  const float gm = gamma[c] * rsqrtf(var + EPSV);
  const float bt = beta[c];
  f16x4 r4 = ((const f16x4*)rec16)[i4];
  float4 xv = ((const float4*)x)[i4];
  float4 o;
  o.x = xv.x + ((float)r4[0] - mean) * gm + bt;
  o.y = xv.y + ((float)r4[1] - mean) * gm + bt;
  o.z = xv.z + ((float)r4[2] - mean) * gm + bt;
  o.w = xv.w + ((float)r4[3] - mean) * gm + bt;
  ((float4*)out)[i4] = o;
}

extern "C" void kernel_launch(void* const* d_in, const int* in_sizes, int n_in,
                              void* d_out, int out_size, void* d_ws, size_t ws_size,
                              hipStream_t stream) {
  const float* x  = (const float*)d_in[0];
  const float* y  = (const float*)d_in[1];
  const float* tw = (const float*)d_in[2];
  const float* tb = (const float*)d_in[3];
  const float* pw = (const float*)d_in[4];
  const float* pb = (const float*)d_in[5];
  const float* gw = (const float*)d_in[6];
  const float* gb = (const float*)d_in[7];
  const float* rw = (const float*)d_in[8];
  const float* rb = (const float*)d_in[9];
  const float* gamma = (const float*)d_in[10];
  const float* beta  = (const float*)d_in[11];
  float* out = (float*)d_out;
  _Float16* xt    = (_Float16*)d_ws;        // 16MB [2][4][4096][256]; dead after proj
  _Float16* w16   = xt + 8388608;           // 256KB [4][32768]
  _Float16* th16  = w16 + 131072;           // 4MB [n][p][ci]
  _Float16* ph16  = th16 + 2097152;         // 4MB [n][p][ci]
  _Float16* g16   = ph16 + 2097152;         // 4MB [n] blocked [128][128][32]
  _Float16* rec16 = g16 + 2097152;          // 8MB [n][c][p]
  float* partial  = (float*)(rec16 + 4194304);  // 1MB [512][512]
  float* stats    = partial + 262144;           // 512 f32
  float2* ml      = (float2*)(stats + 512);     // 512KB [4][4][4096]
  _Float16* po16  = xt;                         // 16MB [4kvq][4n][4096][128] (aliases xt)
  _Float16* rw16 = w16 + 98304;
  pack_w<<<dim3(512), 256, 0, stream>>>(tw, pw, gw, rw, w16);
  pack_xy<<<dim3(512, 4, 2), 256, 0, stream>>>(x, y, xt);
  proj_kernel<<<dim3(32, 12), 256, 0, stream>>>(xt, w16, tb, pb, gb, th16, ph16, g16);
  attn_kernel<<<dim3(512), 256, 0, stream>>>(th16, ph16, g16, po16, ml);
  rec_kernel<<<dim3(128, 4), 256, 0, stream>>>(po16, ml, rw16, rb, rec16, partial);
  stats_reduce<<<dim3(2), 256, 0, stream>>>(partial, stats);
  bn_kernel<<<dim3(4096), 256, 0, stream>>>(x, gamma, beta, stats, rec16, out);
}

// Round 16
// 116.117 us; speedup vs baseline: 1.3757x; 1.1204x over previous
//
#include <hip/hip_runtime.h>
#include <math.h>

#define EPSV 1e-5f

typedef __attribute__((ext_vector_type(8))) _Float16 f16x8;
typedef __attribute__((ext_vector_type(4))) _Float16 f16x4;
typedef __attribute__((ext_vector_type(4))) float f32x4;

typedef __attribute__((address_space(1))) const unsigned int as1_u32;
typedef __attribute__((address_space(3))) unsigned int as3_u32;

static __device__ __forceinline__ unsigned packh2(float a, float b) {
  auto v = __builtin_amdgcn_cvt_pkrtz(a, b);  // __fp16 ext_vector(2)
  return __builtin_bit_cast(unsigned, v);
}

// ---------------- pack x,y fp32 [n][c][p] -> fp16 transposed [src][n][p][c]
// z==2 blocks pack the four weight matrices fp32->fp16 instead.
__global__ __launch_bounds__(256) void pack_xy(
    const float* __restrict__ x, const float* __restrict__ y,
    const float* __restrict__ tw, const float* __restrict__ pw,
    const float* __restrict__ gw, const float* __restrict__ rw,
    _Float16* __restrict__ xt, _Float16* __restrict__ w16) {
  if (blockIdx.z == 2) {
    int i = (blockIdx.y * 512 + blockIdx.x) * 256 + threadIdx.x;
    if (i < 131072) {
      const float* s = i < 32768 ? tw : (i < 65536 ? pw : (i < 98304 ? gw : rw));
      w16[i] = (_Float16)s[i & 32767];
    }
    return;
  }
  const int n = blockIdx.y, s = blockIdx.z;
  const int g = blockIdx.x * 256 + threadIdx.x;  // 131072 per (n,s)
  const int p = g & 4095, c8 = g >> 12;          // c8 0..31
  const float* src = (s ? y : x) + ((size_t)n * 256 + c8 * 8) * 4096 + p;
  f16x8 v;
#pragma unroll
  for (int j = 0; j < 8; ++j) v[j] = (_Float16)src[(size_t)j * 4096];
  *(f16x8*)(xt + ((size_t)(s * 4 + n) * 4096 + p) * 256 + c8 * 8) = v;
}

// ---------------- projections via MFMA, PTILE=64 (768 blocks, 3/CU balanced).
// pr 0 (theta): -> [p][ci]; pr 1 (phi): -> [p][ci]; pr 2 (g): -> blocked [p/32][ci][32]
__global__ __launch_bounds__(256) void proj_kernel(
    const _Float16* __restrict__ xt, const _Float16* __restrict__ w16,
    const float* __restrict__ tb, const float* __restrict__ pb,
    const float* __restrict__ gb, _Float16* __restrict__ th16,
    _Float16* __restrict__ ph16, _Float16* __restrict__ g16) {
  const int ptile = blockIdx.x;  // 64 tiles of 64 positions
  const int z = blockIdx.y;      // 12 = 3 pr * 4 n
  const int pr = z >> 2, n = z & 3;
  const int p0 = ptile * 64;
  const int tid = threadIdx.x, wv = tid >> 6, lane = tid & 63, lg = lane >> 4, lr = lane & 15;

  __shared__ __align__(16) char sB[32768];  // X tile [64 p][256 c] fp16, swz ((p&7)<<4)

  const int srcn = (pr == 1 ? 4 : 0) + n;
  const char* src = (const char*)(xt + ((size_t)srcn * 4096 + p0) * 256);
#pragma unroll
  for (int ps = 0; ps < 8; ++ps) {
    int L = ps * 4096 + tid * 16;
    int row = L >> 9, col = L & 511;
    __builtin_amdgcn_global_load_lds((as1_u32*)(src + (size_t)row * 512 + (col ^ ((row & 7) << 4))),
                                     (as3_u32*)(sB + L), 16, 0, 0);
  }
  const _Float16* wp = w16 + pr * 32768;
  const float* bp = pr == 0 ? tb : (pr == 1 ? pb : gb);

  if (pr == 2) {
    const int o0 = wv * 32;
    f16x8 a[2][8];
#pragma unroll
    for (int mf = 0; mf < 2; ++mf)
#pragma unroll
      for (int kc = 0; kc < 8; ++kc)
        a[mf][kc] = *(const f16x8*)(wp + (size_t)(o0 + mf * 16 + lr) * 256 + kc * 32 + lg * 8);
    __syncthreads();
    f32x4 acc[2][4];
#pragma unroll
    for (int mf = 0; mf < 2; ++mf)
#pragma unroll
      for (int nf = 0; nf < 4; ++nf) acc[mf][nf] = f32x4{0.f, 0.f, 0.f, 0.f};
#pragma unroll
    for (int kc = 0; kc < 8; ++kc) {
      f16x8 bf[4];
#pragma unroll
      for (int nf = 0; nf < 4; ++nf)
        bf[nf] = *(const f16x8*)(sB + (nf * 16 + lr) * 512 + ((kc * 64 + lg * 16) ^ ((lr & 7) << 4)));
#pragma unroll
      for (int mf = 0; mf < 2; ++mf)
#pragma unroll
        for (int nf = 0; nf < 4; ++nf)
          acc[mf][nf] = __builtin_amdgcn_mfma_f32_16x16x32_f16(a[mf][kc], bf[nf], acc[mf][nf], 0, 0, 0);
    }
    // g blocked: [pblk=p>>5][ci][p&31], per n
    _Float16* out = g16 + (size_t)n * 524288;
#pragma unroll
    for (int mf = 0; mf < 2; ++mf)
#pragma unroll
      for (int r = 0; r < 4; ++r) {
        int o = o0 + mf * 16 + lg * 4 + r;
        float bias = bp[o];
#pragma unroll
        for (int nf = 0; nf < 4; ++nf) {
          int pp = p0 + nf * 16 + lr;
          out[(size_t)((pp >> 5) * 128 + o) * 32 + (pp & 31)] = (_Float16)(acc[mf][nf][r] + bias);
        }
      }
  } else {
    __syncthreads();
    // each wave owns 16 p-rows: rows wv*16 .. wv*16+15
    f32x4 acc[8];
#pragma unroll
    for (int nf = 0; nf < 8; ++nf) acc[nf] = f32x4{0.f, 0.f, 0.f, 0.f};
#pragma unroll 2
    for (int kc = 0; kc < 8; ++kc) {
      f16x8 bf[8];
#pragma unroll
      for (int nf = 0; nf < 8; ++nf)
        bf[nf] = *(const f16x8*)(wp + (size_t)(nf * 16 + lr) * 256 + kc * 32 + lg * 8);
      f16x8 af = *(const f16x8*)(sB + (wv * 16 + lr) * 512 + ((kc * 64 + lg * 16) ^ ((lr & 7) << 4)));
#pragma unroll
      for (int nf = 0; nf < 8; ++nf)
        acc[nf] = __builtin_amdgcn_mfma_f32_16x16x32_f16(af, bf[nf], acc[nf], 0, 0, 0);
    }
    _Float16* out = (pr == 0 ? th16 : ph16) + (size_t)n * 4096 * 128;
#pragma unroll
    for (int r = 0; r < 4; ++r) {
      int p = p0 + wv * 16 + lg * 4 + r;
#pragma unroll
      for (int nf = 0; nf < 8; ++nf) {
        int o = nf * 16 + lr;
        out[(size_t)p * 128 + o] = (_Float16)(acc[nf][r] + bp[o]);
      }
    }
  }
}

// ---------------- flash attention: 512 blocks, 4 waves x 32q (2 qg), KVBLK=32,
// each block owns one KV quarter (1024 kpos, 32 iters). r12-proven structure.
__global__ __launch_bounds__(256, 2) void attn_kernel(
    const _Float16* __restrict__ th16, const _Float16* __restrict__ ph16,
    const _Float16* __restrict__ g16, _Float16* __restrict__ po16,
    float2* __restrict__ ml) {
  const int lin = blockIdx.x;  // 512
  const int xcd = lin & 7;     // (n,kv-half) per XCD -> K/G slices L2-resident
  const int n = xcd >> 1;
  const int kvh = xcd & 1;
  const int rest = lin >> 3;   // 0..63
  const int qt = rest >> 1;    // 0..31
  const int kvq = kvh * 2 + (rest & 1);
  const int q0 = qt * 128;
  const int tid = threadIdx.x;
  const int wv = tid >> 6, lane = tid & 63, lg = lane >> 4, lr = lane & 15;
  const int kv0 = kvq * 1024;

  // K dbuf 2x8KB @0 | G dbuf 2x8KB @16384 | P 4wv x 2qg x 1KB @32768  (=40KB)
  __shared__ __align__(16) char smem[40960];
#define KBUF(B) (smem + (B) * 8192)
#define GBUF(B) (smem + 16384 + (B) * 8192)
  char* pB = smem + 32768 + wv * 2048;

  const _Float16* thn = th16 + (size_t)n * 4096 * 128;             // [p][ci]
  const char* phn = (const char*)(ph16 + (size_t)n * 4096 * 128);  // [p][ci]
  const char* ggn = (const char*)(g16 + (size_t)n * 524288);       // blocked [128][128][32]

  // pre-swizzled staging sources (linear LDS dest + inverse-swz source + swz reads)
  // K: 32 rows x 256B, swz (row&7)<<4 ; G: 128 rows x 64B, swz ((row>>1)&3)<<4
  const char* ksrc = phn + (size_t)kv0 * 256 + (tid >> 4) * 256 +
                     (((tid & 15) * 16) ^ (((tid >> 4) & 7) << 4));
  const char* gsrc = ggn + (size_t)kvq * 262144 + (tid >> 2) * 64 +
                     (((tid & 3) * 16) ^ (((tid >> 3) & 3) << 4));

#define STAGE(KT, B)                                                                     \
  do {                                                                                   \
    const char* ks = ksrc + (size_t)(KT) * 8192;                                         \
    const char* gs = gsrc + (size_t)(KT) * 8192;                                         \
    char* kd = KBUF(B) + tid * 16;                                                       \
    char* gd = GBUF(B) + tid * 16;                                                       \
    __builtin_amdgcn_global_load_lds((as1_u32*)ks, (as3_u32*)kd, 16, 0, 0);              \
    __builtin_amdgcn_global_load_lds((as1_u32*)(ks + 4096), (as3_u32*)(kd + 4096), 16, 0, 0); \
    __builtin_amdgcn_global_load_lds((as1_u32*)gs, (as3_u32*)gd, 16, 0, 0);              \
    __builtin_amdgcn_global_load_lds((as1_u32*)(gs + 4096), (as3_u32*)(gd + 4096), 16, 0, 0); \
  } while (0)

  // Q fragments (B-operand): B[k=ci][q=lr] per qg, vector loads from [p][ci]
  f16x8 qf[2][4];
#pragma unroll
  for (int qg = 0; qg < 2; ++qg)
#pragma unroll
    for (int ch = 0; ch < 4; ++ch)
      qf[qg][ch] = *(const f16x8*)(thn + (size_t)(q0 + wv * 32 + qg * 16 + lr) * 128 +
                                   ch * 32 + lg * 8);

  const int swzk = (lr & 7) << 4;         // K 256B rows
  const int swzg = ((lr >> 1) & 3) << 4;  // G 64B rows (balanced)
  const int swzp = ((lr >> 1) & 3) << 4;  // P 64B rows (balanced)

  f32x4 acc[2][8];
#pragma unroll
  for (int qg = 0; qg < 2; ++qg)
#pragma unroll
    for (int of = 0; of < 8; ++of) acc[qg][of] = f32x4{0.f, 0.f, 0.f, 0.f};
  float m[2] = {-INFINITY, -INFINITY};
  float lrow[2] = {0.f, 0.f};  // lane-partial; summed across lg at epilogue

  STAGE(0, 0);
  __syncthreads();

  for (int kt = 0; kt < 32; ++kt) {
    const int b = kt & 1;
    if (kt < 31) STAGE(kt + 1, b ^ 1);

    // QK: S^T[k=cf*16+lg*4+r][q=lr] per qg; each K frag feeds both qg
    const char* kb = KBUF(b);
    f32x4 s[2][2];
#pragma unroll
    for (int cf = 0; cf < 2; ++cf) {
      s[cf][0] = f32x4{0.f, 0.f, 0.f, 0.f};
      s[cf][1] = f32x4{0.f, 0.f, 0.f, 0.f};
    }
    __builtin_amdgcn_s_setprio(1);
#pragma unroll
    for (int cf = 0; cf < 2; ++cf) {
      const char* krow = kb + (cf * 16 + lr) * 256;
#pragma unroll
      for (int ch = 0; ch < 4; ++ch) {
        f16x8 kf = *(const f16x8*)(krow + ((ch * 64 + lg * 16) ^ swzk));
        s[cf][0] = __builtin_amdgcn_mfma_f32_16x16x32_f16(kf, qf[0][ch], s[cf][0], 0, 0, 0);
        s[cf][1] = __builtin_amdgcn_mfma_f32_16x16x32_f16(kf, qf[1][ch], s[cf][1], 0, 0, 0);
      }
    }
    __builtin_amdgcn_s_setprio(0);

    // lane-local max per qg; cross-lane reduce only when the __all gate fails
    float mt0 = fmaxf(fmaxf(fmaxf(s[0][0][0], s[0][0][1]), fmaxf(s[0][0][2], s[0][0][3])),
                      fmaxf(fmaxf(s[1][0][0], s[1][0][1]), fmaxf(s[1][0][2], s[1][0][3])));
    float mt1 = fmaxf(fmaxf(fmaxf(s[0][1][0], s[0][1][1]), fmaxf(s[0][1][2], s[0][1][3])),
                      fmaxf(fmaxf(s[1][1][0], s[1][1][1]), fmaxf(s[1][1][2], s[1][1][3])));
    bool ok = (mt0 <= m[0] + 8.0f) && (mt1 <= m[1] + 8.0f);
    if (!__all(ok)) {
      // group max over the 4 lanes sharing q (lg dimension)
      mt0 = fmaxf(mt0, __shfl_xor(mt0, 16)); mt0 = fmaxf(mt0, __shfl_xor(mt0, 32));
      mt1 = fmaxf(mt1, __shfl_xor(mt1, 16)); mt1 = fmaxf(mt1, __shfl_xor(mt1, 32));
      float mn0 = fmaxf(m[0], mt0), mn1 = fmaxf(m[1], mt1);
      float sc0 = __expf(m[0] - mn0), sc1 = __expf(m[1] - mn1);
#pragma unroll
      for (int of = 0; of < 8; ++of) { acc[0][of] *= sc0; acc[1][of] *= sc1; }
      lrow[0] *= sc0; lrow[1] *= sc1;
      m[0] = mn0; m[1] = mn1;
    }
#pragma unroll
    for (int qg = 0; qg < 2; ++qg) {
      char* prow = pB + qg * 1024 + lr * 64;
      float psum = 0.f;
#pragma unroll
      for (int cf = 0; cf < 2; ++cf) {
        float p0 = __expf(s[cf][qg][0] - m[qg]);
        float p1 = __expf(s[cf][qg][1] - m[qg]);
        float p2 = __expf(s[cf][qg][2] - m[qg]);
        float p3 = __expf(s[cf][qg][3] - m[qg]);
        psum += (p0 + p1) + (p2 + p3);
        unsigned long long w = (unsigned long long)packh2(p0, p1) |
                               ((unsigned long long)packh2(p2, p3) << 32);
        *(unsigned long long*)(prow + ((cf * 32 + lg * 8) ^ swzp)) = w;
      }
      lrow[qg] += psum;  // lane-partial; no shfl here
    }

    // PV: O^T[ci][q] += G * P^T per qg; each G frag feeds both qg
    const char* gb = GBUF(b);
    f16x8 pf0 = *(const f16x8*)(pB + lr * 64 + ((lg * 16) ^ swzp));
    f16x8 pf1 = *(const f16x8*)(pB + 1024 + lr * 64 + ((lg * 16) ^ swzp));
    __builtin_amdgcn_s_setprio(1);
#pragma unroll
    for (int of = 0; of < 8; ++of) {
      f16x8 gf = *(const f16x8*)(gb + (of * 16 + lr) * 64 + ((lg * 16) ^ swzg));
      acc[0][of] = __builtin_amdgcn_mfma_f32_16x16x32_f16(gf, pf0, acc[0][of], 0, 0, 0);
      acc[1][of] = __builtin_amdgcn_mfma_f32_16x16x32_f16(gf, pf1, acc[1][of], 0, 0, 0);
    }
    __builtin_amdgcn_s_setprio(0);
    __syncthreads();  // drains stage(kt+1); all waves done with buf b
  }

  // finalize l: sum lane-partials across the 4 lanes sharing each q
  float L0 = lrow[0];
  L0 += __shfl_xor(L0, 16); L0 += __shfl_xor(L0, 32);
  float L1 = lrow[1];
  L1 += __shfl_xor(L1, 16); L1 += __shfl_xor(L1, 32);

  // epilogue: transpose O^T -> [q][ci] through LDS; fp16 partial + (m,l)
  float* ep = (float*)(smem + wv * 8448);  // 16 rows x 132 f32, per wave
#pragma unroll
  for (int qg = 0; qg < 2; ++qg) {
#pragma unroll
    for (int of = 0; of < 8; ++of)
#pragma unroll
      for (int r = 0; r < 4; ++r) ep[lr * 132 + of * 16 + lg * 4 + r] = acc[qg][of][r];
    char* pon = (char*)(po16 + ((size_t)(kvq * 4 + n) * 4096 + q0 + wv * 32 + qg * 16) * 128);
#pragma unroll
    for (int it = 0; it < 4; ++it) {
      int e = lane + it * 64;
      int qq = e >> 4, c8 = e & 15;
      f32x4 va = *(const f32x4*)(ep + qq * 132 + c8 * 8);
      f32x4 vb = *(const f32x4*)(ep + qq * 132 + c8 * 8 + 4);
      f16x8 h;
#pragma unroll
      for (int j = 0; j < 4; ++j) { h[j] = (_Float16)va[j]; h[4 + j] = (_Float16)vb[j]; }
      *(f16x8*)(pon + (size_t)qq * 256 + c8 * 16) = h;
    }
    if (lg == 0)
      ml[(size_t)(kvq * 4 + n) * 4096 + q0 + wv * 32 + qg * 16 + lr] =
          float2{m[qg], qg == 0 ? L0 : L1};
  }
#undef STAGE
#undef KBUF
#undef GBUF
}

// ---------------- rec projection (MFMA) with FUSED 4-way merge + BN partial stats
__global__ __launch_bounds__(256) void rec_kernel(
    const _Float16* __restrict__ po16, const float2* __restrict__ ml,
    const _Float16* __restrict__ rw16, const float* __restrict__ rb,
    _Float16* __restrict__ rec16, float* __restrict__ partial) {
  const int pblk = blockIdx.x;  // 128 tiles of 32 positions
  const int n = blockIdx.y;
  const int p0 = pblk * 32;
  const int blin = n * 128 + pblk;  // 0..511
  const int tid = threadIdx.x, wv = tid >> 6, lane = tid & 63, lg = lane >> 4, lr = lane & 15;
  __shared__ __align__(16) char sB[8192];  // merged O tile [32 p][128 ci] fp16, swz ((p&7)<<4)

  // ---- fused merge staging: each thread merges one 16-ci segment of one row
  {
    const int row = tid >> 3;       // p within tile, 0..31
    const int c0 = (tid & 7) * 16;  // ci start
    float2 v[4];
    float M = -INFINITY;
#pragma unroll
    for (int k = 0; k < 4; ++k) {
      v[k] = ml[(size_t)(k * 4 + n) * 4096 + p0 + row];
      M = fmaxf(M, v[k].x);
    }
    float f[4], L = 0.f;
#pragma unroll
    for (int k = 0; k < 4; ++k) {
      f[k] = __expf(v[k].x - M);
      L += v[k].y * f[k];
    }
    const float inv = 1.0f / L;
    float o[16];
#pragma unroll
    for (int j = 0; j < 16; ++j) o[j] = 0.f;
#pragma unroll
    for (int k = 0; k < 4; ++k) {
      const _Float16* p = po16 + ((size_t)(k * 4 + n) * 4096 + p0 + row) * 128 + c0;
      f16x8 a = *(const f16x8*)p;
      f16x8 b = *(const f16x8*)(p + 8);
#pragma unroll
      for (int j = 0; j < 8; ++j) {
        o[j] += f[k] * (float)a[j];
        o[8 + j] += f[k] * (float)b[j];
      }
    }
    f16x8 h0, h1;
#pragma unroll
    for (int j = 0; j < 8; ++j) {
      h0[j] = (_Float16)(o[j] * inv);
      h1[j] = (_Float16)(o[8 + j] * inv);
    }
    char* dst = sB + row * 256;
    const int xr = (row & 7) << 4;
    *(f16x8*)(dst + ((c0 * 2) ^ xr)) = h0;
    *(f16x8*)(dst + ((c0 * 2 + 16) ^ xr)) = h1;
  }

  const int wc0 = wv * 64;
  f16x8 a[4][4];
#pragma unroll
  for (int mf = 0; mf < 4; ++mf)
#pragma unroll
    for (int kc = 0; kc < 4; ++kc)
      a[mf][kc] = *(const f16x8*)(rw16 + (size_t)(wc0 + mf * 16 + lr) * 128 + kc * 32 + lg * 8);
  __syncthreads();

  f32x4 acc[4][2];
#pragma unroll
  for (int mf = 0; mf < 4; ++mf) {
    acc[mf][0] = f32x4{0.f, 0.f, 0.f, 0.f};
    acc[mf][1] = f32x4{0.f, 0.f, 0.f, 0.f};
  }
  const int xorv = (lr & 7) << 4;
#pragma unroll
  for (int kc = 0; kc < 4; ++kc) {
    int cb = (kc * 64 + lg * 16) ^ xorv;
    f16x8 b0 = *(const f16x8*)(sB + lr * 256 + cb);
    f16x8 b1 = *(const f16x8*)(sB + (16 + lr) * 256 + cb);
#pragma unroll
    for (int mf = 0; mf < 4; ++mf) {
      acc[mf][0] = __builtin_amdgcn_mfma_f32_16x16x32_f16(a[mf][kc], b0, acc[mf][0], 0, 0, 0);
      acc[mf][1] = __builtin_amdgcn_mfma_f32_16x16x32_f16(a[mf][kc], b1, acc[mf][1], 0, 0, 0);
    }
  }
  float* pslot = partial + (size_t)blin * 512;
#pragma unroll
  for (int mf = 0; mf < 4; ++mf)
#pragma unroll
    for (int r = 0; r < 4; ++r) {
      int c = wc0 + mf * 16 + lg * 4 + r;
      float bias = rb[c];
      float v0 = acc[mf][0][r] + bias;
      float v1 = acc[mf][1][r] + bias;
      rec16[((size_t)n * 256 + c) * 4096 + p0 + lr] = (_Float16)v0;
      rec16[((size_t)n * 256 + c) * 4096 + p0 + 16 + lr] = (_Float16)v1;
      float s = v0 + v1, qd = v0 * v0 + v1 * v1;
      s += __shfl_xor(s, 1); qd += __shfl_xor(qd, 1);
      s += __shfl_xor(s, 2); qd += __shfl_xor(qd, 2);
      s += __shfl_xor(s, 4); qd += __shfl_xor(qd, 4);
      s += __shfl_xor(s, 8); qd += __shfl_xor(qd, 8);
      if (lr == 0) {
        pslot[c] = s;
        pslot[256 + c] = qd;
      }
    }
}

// ---------------- reduce per-block partials -> stats[512] (16 blocks, 8 lanes/stat)
__global__ __launch_bounds__(256) void stats_reduce(const float* __restrict__ partial,
                                                    float* __restrict__ stats) {
  const int tid = threadIdx.x;
  const int j = blockIdx.x * 32 + (tid >> 3);  // 0..511
  const int sub = tid & 7;
  float s = 0.f;
#pragma unroll 8
  for (int i = 0; i < 64; ++i) s += partial[(size_t)(i * 8 + sub) * 512 + j];
  s += __shfl_xor(s, 1);
  s += __shfl_xor(s, 2);
  s += __shfl_xor(s, 4);
  if (sub == 0) stats[j] = s;
}

// ---------------- BN apply + residual (reads fp16 rec result)
__global__ __launch_bounds__(256) void bn_kernel(
    const float* __restrict__ x, const float* __restrict__ gamma,
    const float* __restrict__ beta, const float* __restrict__ stats,
    const _Float16* __restrict__ rec16, float* __restrict__ out) {
  const size_t i4 = (size_t)blockIdx.x * 256 + threadIdx.x;
  const int c = (int)((i4 >> 10) & 255);
  const float inv = 1.f / 16384.f;
  const float mean = stats[c] * inv;
  const float var = stats[256 + c] * inv - mean * mean;
  const float gm = gamma[c] * rsqrtf(var + EPSV);
  const float bt = beta[c];
  f16x4 r4 = ((const f16x4*)rec16)[i4];
  float4 xv = ((const float4*)x)[i4];
  float4 o;
  o.x = xv.x + ((float)r4[0] - mean) * gm + bt;
  o.y = xv.y + ((float)r4[1] - mean) * gm + bt;
  o.z = xv.z + ((float)r4[2] - mean) * gm + bt;
  o.w = xv.w + ((float)r4[3] - mean) * gm + bt;
  ((float4*)out)[i4] = o;
}

extern "C" void kernel_launch(void* const* d_in, const int* in_sizes, int n_in,
                              void* d_out, int out_size, void* d_ws, size_t ws_size,
                              hipStream_t stream) {
  const float* x  = (const float*)d_in[0];
  const float* y  = (const float*)d_in[1];
  const float* tw = (const float*)d_in[2];
  const float* tb = (const float*)d_in[3];
  const float* pw = (const float*)d_in[4];
  const float* pb = (const float*)d_in[5];
  const float* gw = (const float*)d_in[6];
  const float* gb = (const float*)d_in[7];
  const float* rw = (const float*)d_in[8];
  const float* rb = (const float*)d_in[9];
  const float* gamma = (const float*)d_in[10];
  const float* beta  = (const float*)d_in[11];
  float* out = (float*)d_out;
  _Float16* xt    = (_Float16*)d_ws;        // 16MB [2][4][4096][256]; dead after proj
  _Float16* w16   = xt + 8388608;           // 256KB [4][32768]
  _Float16* th16  = w16 + 131072;           // 4MB [n][p][ci]
  _Float16* ph16  = th16 + 2097152;         // 4MB [n][p][ci]
  _Float16* g16   = ph16 + 2097152;         // 4MB [n] blocked [128][128][32]
  _Float16* rec16 = g16 + 2097152;          // 8MB [n][c][p]
  float* partial  = (float*)(rec16 + 4194304);  // 1MB [512][512]
  float* stats    = partial + 262144;           // 512 f32
  float2* ml      = (float2*)(stats + 512);     // 512KB [4][4][4096]
  _Float16* po16  = xt;                         // 16MB [4kvq][4n][4096][128] (aliases xt)
  _Float16* rw16 = w16 + 98304;
  pack_xy<<<dim3(512, 4, 3), 256, 0, stream>>>(x, y, tw, pw, gw, rw, xt, w16);
  proj_kernel<<<dim3(64, 12), 256, 0, stream>>>(xt, w16, tb, pb, gb, th16, ph16, g16);
  attn_kernel<<<dim3(512), 256, 0, stream>>>(th16, ph16, g16, po16, ml);
  rec_kernel<<<dim3(128, 4), 256, 0, stream>>>(po16, ml, rw16, rb, rec16, partial);
  stats_reduce<<<dim3(16), 256, 0, stream>>>(partial, stats);
  bn_kernel<<<dim3(4096), 256, 0, stream>>>(x, gamma, beta, stats, rec16, out);
}

// Round 17
// 112.658 us; speedup vs baseline: 1.4179x; 1.0307x over previous
//
#include <hip/hip_runtime.h>
#include <math.h>

#define EPSV 1e-5f

typedef __attribute__((ext_vector_type(8))) _Float16 f16x8;
typedef __attribute__((ext_vector_type(4))) _Float16 f16x4;
typedef __attribute__((ext_vector_type(4))) float f32x4;

typedef __attribute__((address_space(1))) const unsigned int as1_u32;
typedef __attribute__((address_space(3))) unsigned int as3_u32;

static __device__ __forceinline__ unsigned packh2(float a, float b) {
  auto v = __builtin_amdgcn_cvt_pkrtz(a, b);  // __fp16 ext_vector(2)
  return __builtin_bit_cast(unsigned, v);
}

// ---------------- pack x,y fp32 [n][c][p] -> fp16 transposed [src][n][p][c]
// z==2 blocks pack the four weight matrices fp32->fp16 instead.
__global__ __launch_bounds__(256) void pack_xy(
    const float* __restrict__ x, const float* __restrict__ y,
    const float* __restrict__ tw, const float* __restrict__ pw,
    const float* __restrict__ gw, const float* __restrict__ rw,
    _Float16* __restrict__ xt, _Float16* __restrict__ w16) {
  if (blockIdx.z == 2) {
    int i = (blockIdx.y * 512 + blockIdx.x) * 256 + threadIdx.x;
    if (i < 131072) {
      const float* s = i < 32768 ? tw : (i < 65536 ? pw : (i < 98304 ? gw : rw));
      w16[i] = (_Float16)s[i & 32767];
    }
    return;
  }
  const int n = blockIdx.y, s = blockIdx.z;
  const int g = blockIdx.x * 256 + threadIdx.x;  // 131072 per (n,s)
  const int p = g & 4095, c8 = g >> 12;          // c8 0..31
  const float* src = (s ? y : x) + ((size_t)n * 256 + c8 * 8) * 4096 + p;
  f16x8 v;
#pragma unroll
  for (int j = 0; j < 8; ++j) v[j] = (_Float16)src[(size_t)j * 4096];
  *(f16x8*)(xt + ((size_t)(s * 4 + n) * 4096 + p) * 256 + c8 * 8) = v;
}

// ---------------- projections via MFMA, PTILE=64 (768 blocks, 3/CU balanced).
// pr 0 (theta): -> [p][ci]; pr 1 (phi): -> [p][ci]; pr 2 (g): -> blocked [p/32][ci][32]
__global__ __launch_bounds__(256) void proj_kernel(
    const _Float16* __restrict__ xt, const _Float16* __restrict__ w16,
    const float* __restrict__ tb, const float* __restrict__ pb,
    const float* __restrict__ gb, _Float16* __restrict__ th16,
    _Float16* __restrict__ ph16, _Float16* __restrict__ g16) {
  const int ptile = blockIdx.x;  // 64 tiles of 64 positions
  const int z = blockIdx.y;      // 12 = 3 pr * 4 n
  const int pr = z >> 2, n = z & 3;
  const int p0 = ptile * 64;
  const int tid = threadIdx.x, wv = tid >> 6, lane = tid & 63, lg = lane >> 4, lr = lane & 15;

  __shared__ __align__(16) char sB[32768];  // X tile [64 p][256 c] fp16, swz ((p&7)<<4)

  const int srcn = (pr == 1 ? 4 : 0) + n;
  const char* src = (const char*)(xt + ((size_t)srcn * 4096 + p0) * 256);
#pragma unroll
  for (int ps = 0; ps < 8; ++ps) {
    int L = ps * 4096 + tid * 16;
    int row = L >> 9, col = L & 511;
    __builtin_amdgcn_global_load_lds((as1_u32*)(src + (size_t)row * 512 + (col ^ ((row & 7) << 4))),
                                     (as3_u32*)(sB + L), 16, 0, 0);
  }
  const _Float16* wp = w16 + pr * 32768;
  const float* bp = pr == 0 ? tb : (pr == 1 ? pb : gb);

  if (pr == 2) {
    const int o0 = wv * 32;
    f16x8 a[2][8];
#pragma unroll
    for (int mf = 0; mf < 2; ++mf)
#pragma unroll
      for (int kc = 0; kc < 8; ++kc)
        a[mf][kc] = *(const f16x8*)(wp + (size_t)(o0 + mf * 16 + lr) * 256 + kc * 32 + lg * 8);
    __syncthreads();
    f32x4 acc[2][4];
#pragma unroll
    for (int mf = 0; mf < 2; ++mf)
#pragma unroll
      for (int nf = 0; nf < 4; ++nf) acc[mf][nf] = f32x4{0.f, 0.f, 0.f, 0.f};
#pragma unroll
    for (int kc = 0; kc < 8; ++kc) {
      f16x8 bf[4];
#pragma unroll
      for (int nf = 0; nf < 4; ++nf)
        bf[nf] = *(const f16x8*)(sB + (nf * 16 + lr) * 512 + ((kc * 64 + lg * 16) ^ ((lr & 7) << 4)));
#pragma unroll
      for (int mf = 0; mf < 2; ++mf)
#pragma unroll
        for (int nf = 0; nf < 4; ++nf)
          acc[mf][nf] = __builtin_amdgcn_mfma_f32_16x16x32_f16(a[mf][kc], bf[nf], acc[mf][nf], 0, 0, 0);
    }
    // g blocked: [pblk=p>>5][ci][p&31], per n
    _Float16* out = g16 + (size_t)n * 524288;
#pragma unroll
    for (int mf = 0; mf < 2; ++mf)
#pragma unroll
      for (int r = 0; r < 4; ++r) {
        int o = o0 + mf * 16 + lg * 4 + r;
        float bias = bp[o];
#pragma unroll
        for (int nf = 0; nf < 4; ++nf) {
          int pp = p0 + nf * 16 + lr;
          out[(size_t)((pp >> 5) * 128 + o) * 32 + (pp & 31)] = (_Float16)(acc[mf][nf][r] + bias);
        }
      }
  } else {
    __syncthreads();
    // each wave owns 16 p-rows: rows wv*16 .. wv*16+15
    f32x4 acc[8];
#pragma unroll
    for (int nf = 0; nf < 8; ++nf) acc[nf] = f32x4{0.f, 0.f, 0.f, 0.f};
#pragma unroll 2
    for (int kc = 0; kc < 8; ++kc) {
      f16x8 bf[8];
#pragma unroll
      for (int nf = 0; nf < 8; ++nf)
        bf[nf] = *(const f16x8*)(wp + (size_t)(nf * 16 + lr) * 256 + kc * 32 + lg * 8);
      f16x8 af = *(const f16x8*)(sB + (wv * 16 + lr) * 512 + ((kc * 64 + lg * 16) ^ ((lr & 7) << 4)));
#pragma unroll
      for (int nf = 0; nf < 8; ++nf)
        acc[nf] = __builtin_amdgcn_mfma_f32_16x16x32_f16(af, bf[nf], acc[nf], 0, 0, 0);
    }
    _Float16* out = (pr == 0 ? th16 : ph16) + (size_t)n * 4096 * 128;
#pragma unroll
    for (int r = 0; r < 4; ++r) {
      int p = p0 + wv * 16 + lg * 4 + r;
#pragma unroll
      for (int nf = 0; nf < 8; ++nf) {
        int o = nf * 16 + lr;
        out[(size_t)p * 128 + o] = (_Float16)(acc[nf][r] + bp[o]);
      }
    }
  }
}

// ---------------- flash attention: 512 blocks, 4 waves x 32q (2 qg), KVBLK=64,
// each block owns one KV quarter (1024 kpos, 16 iters). r12 inner math, halved
// per-iter fixed costs (barriers/gates/loop).
__global__ __launch_bounds__(256, 2) void attn_kernel(
    const _Float16* __restrict__ th16, const _Float16* __restrict__ ph16,
    const _Float16* __restrict__ g16, _Float16* __restrict__ po16,
    float2* __restrict__ ml) {
  const int lin = blockIdx.x;  // 512
  const int xcd = lin & 7;     // (n,kv-half) per XCD -> K/G slices L2-resident
  const int n = xcd >> 1;
  const int kvh = xcd & 1;
  const int rest = lin >> 3;   // 0..63
  const int qt = rest >> 1;    // 0..31
  const int kvq = kvh * 2 + (rest & 1);
  const int q0 = qt * 128;
  const int tid = threadIdx.x;
  const int wv = tid >> 6, lane = tid & 63, lg = lane >> 4, lr = lane & 15;
  const int kv0 = kvq * 1024;

  // K dbuf 2x16KB @0 | G dbuf 2x16KB @32768 | P 4wv x 2qg x 2KB @65536  (=80KB)
  __shared__ __align__(16) char smem[81920];
#define KBUF(B) (smem + (B) * 16384)
#define GBUF(B) (smem + 32768 + (B) * 16384)
  char* pB = smem + 65536 + wv * 4096;

  const _Float16* thn = th16 + (size_t)n * 4096 * 128;             // [p][ci]
  const char* phn = (const char*)(ph16 + (size_t)n * 4096 * 128);  // [p][ci]
  const char* ggn = (const char*)(g16 + (size_t)n * 524288);       // blocked [128][128][32]

  // pre-swizzled staging sources (linear LDS dest + inverse-swz source + swz reads)
  // K: 64 rows x 256B, swz (row&7)<<4 ; G: 256 rows x 64B, swz ((row>>1)&3)<<4
  const char* ksrc = phn + (size_t)kv0 * 256 + (tid >> 4) * 256 +
                     (((tid & 15) * 16) ^ (((tid >> 4) & 7) << 4));
  const char* gsrc = ggn + (size_t)kvq * 262144 + (tid >> 2) * 64 +
                     (((tid & 3) * 16) ^ (((tid >> 3) & 3) << 4));

#define STAGE(KT, B)                                                                     \
  do {                                                                                   \
    const char* ks = ksrc + (size_t)(KT) * 16384;                                        \
    const char* gs = gsrc + (size_t)(KT) * 16384;                                        \
    char* kd = KBUF(B) + tid * 16;                                                       \
    char* gd = GBUF(B) + tid * 16;                                                       \
    _Pragma("unroll") for (int i_ = 0; i_ < 4; ++i_) {                                   \
      __builtin_amdgcn_global_load_lds((as1_u32*)(ks + i_ * 4096),                       \
                                       (as3_u32*)(kd + i_ * 4096), 16, 0, 0);            \
      __builtin_amdgcn_global_load_lds((as1_u32*)(gs + i_ * 4096),                       \
                                       (as3_u32*)(gd + i_ * 4096), 16, 0, 0);            \
    }                                                                                    \
  } while (0)

  // Q fragments (B-operand): B[k=ci][q=lr] per qg, vector loads from [p][ci]
  f16x8 qf[2][4];
#pragma unroll
  for (int qg = 0; qg < 2; ++qg)
#pragma unroll
    for (int ch = 0; ch < 4; ++ch)
      qf[qg][ch] = *(const f16x8*)(thn + (size_t)(q0 + wv * 32 + qg * 16 + lr) * 128 +
                                   ch * 32 + lg * 8);

  const int swzk = (lr & 7) << 4;         // K 256B rows
  const int swzg = ((lr >> 1) & 3) << 4;  // G 64B rows (balanced)
  const int swzp = (lr & 7) << 4;         // P 128B rows, 3-bit key

  f32x4 acc[2][8];
#pragma unroll
  for (int qg = 0; qg < 2; ++qg)
#pragma unroll
    for (int of = 0; of < 8; ++of) acc[qg][of] = f32x4{0.f, 0.f, 0.f, 0.f};
  float m[2] = {-INFINITY, -INFINITY};
  float lrow[2] = {0.f, 0.f};  // lane-partial; summed across lg at epilogue

  STAGE(0, 0);
  __syncthreads();

  for (int kt = 0; kt < 16; ++kt) {
    const int b = kt & 1;
    if (kt < 15) STAGE(kt + 1, b ^ 1);

    // QK: S^T[k=cf*16+lg*4+r][q=lr] per qg; each K frag feeds both qg
    const char* kb = KBUF(b);
    f32x4 s[4][2];
#pragma unroll
    for (int cf = 0; cf < 4; ++cf) {
      s[cf][0] = f32x4{0.f, 0.f, 0.f, 0.f};
      s[cf][1] = f32x4{0.f, 0.f, 0.f, 0.f};
    }
    __builtin_amdgcn_s_setprio(1);
#pragma unroll
    for (int cf = 0; cf < 4; ++cf) {
      const char* krow = kb + (cf * 16 + lr) * 256;
#pragma unroll
      for (int ch = 0; ch < 4; ++ch) {
        f16x8 kf = *(const f16x8*)(krow + ((ch * 64 + lg * 16) ^ swzk));
        s[cf][0] = __builtin_amdgcn_mfma_f32_16x16x32_f16(kf, qf[0][ch], s[cf][0], 0, 0, 0);
        s[cf][1] = __builtin_amdgcn_mfma_f32_16x16x32_f16(kf, qf[1][ch], s[cf][1], 0, 0, 0);
      }
    }
    __builtin_amdgcn_s_setprio(0);

    // lane-local max per qg; cross-lane reduce only when the __all gate fails
    float mt0 = s[0][0][0], mt1 = s[0][1][0];
#pragma unroll
    for (int cf = 0; cf < 4; ++cf)
#pragma unroll
      for (int r = 0; r < 4; ++r) {
        mt0 = fmaxf(mt0, s[cf][0][r]);
        mt1 = fmaxf(mt1, s[cf][1][r]);
      }
    bool ok = (mt0 <= m[0] + 8.0f) && (mt1 <= m[1] + 8.0f);
    if (!__all(ok)) {
      // group max over the 4 lanes sharing q (lg dimension)
      mt0 = fmaxf(mt0, __shfl_xor(mt0, 16)); mt0 = fmaxf(mt0, __shfl_xor(mt0, 32));
      mt1 = fmaxf(mt1, __shfl_xor(mt1, 16)); mt1 = fmaxf(mt1, __shfl_xor(mt1, 32));
      float mn0 = fmaxf(m[0], mt0), mn1 = fmaxf(m[1], mt1);
      float sc0 = __expf(m[0] - mn0), sc1 = __expf(m[1] - mn1);
#pragma unroll
      for (int of = 0; of < 8; ++of) { acc[0][of] *= sc0; acc[1][of] *= sc1; }
      lrow[0] *= sc0; lrow[1] *= sc1;
      m[0] = mn0; m[1] = mn1;
    }
#pragma unroll
    for (int qg = 0; qg < 2; ++qg) {
      char* prow = pB + qg * 2048 + lr * 128;
      float psum = 0.f;
#pragma unroll
      for (int cf = 0; cf < 4; ++cf) {
        float p0 = __expf(s[cf][qg][0] - m[qg]);
        float p1 = __expf(s[cf][qg][1] - m[qg]);
        float p2 = __expf(s[cf][qg][2] - m[qg]);
        float p3 = __expf(s[cf][qg][3] - m[qg]);
        psum += (p0 + p1) + (p2 + p3);
        unsigned long long w = (unsigned long long)packh2(p0, p1) |
                               ((unsigned long long)packh2(p2, p3) << 32);
        *(unsigned long long*)(prow + ((cf * 32 + lg * 8) ^ swzp)) = w;
      }
      lrow[qg] += psum;  // lane-partial; no shfl here
    }

    // PV: O^T[ci][q] += G * P^T per qg; each G frag feeds both qg
    const char* gb = GBUF(b);
#pragma unroll
    for (int kc = 0; kc < 2; ++kc) {
      f16x8 pf0 = *(const f16x8*)(pB + lr * 128 + ((kc * 64 + lg * 16) ^ swzp));
      f16x8 pf1 = *(const f16x8*)(pB + 2048 + lr * 128 + ((kc * 64 + lg * 16) ^ swzp));
      __builtin_amdgcn_s_setprio(1);
#pragma unroll
      for (int of = 0; of < 8; ++of) {
        f16x8 gf = *(const f16x8*)(gb + kc * 8192 + (of * 16 + lr) * 64 + ((lg * 16) ^ swzg));
        acc[0][of] = __builtin_amdgcn_mfma_f32_16x16x32_f16(gf, pf0, acc[0][of], 0, 0, 0);
        acc[1][of] = __builtin_amdgcn_mfma_f32_16x16x32_f16(gf, pf1, acc[1][of], 0, 0, 0);
      }
      __builtin_amdgcn_s_setprio(0);
    }
    __syncthreads();  // drains stage(kt+1); all waves done with buf b
  }

  // finalize l: sum lane-partials across the 4 lanes sharing each q
  float L0 = lrow[0];
  L0 += __shfl_xor(L0, 16); L0 += __shfl_xor(L0, 32);
  float L1 = lrow[1];
  L1 += __shfl_xor(L1, 16); L1 += __shfl_xor(L1, 32);

  // epilogue: transpose O^T -> [q][ci] through LDS; fp16 partial + (m,l)
  float* ep = (float*)(smem + wv * 8448);  // 16 rows x 132 f32, per wave
#pragma unroll
  for (int qg = 0; qg < 2; ++qg) {
#pragma unroll
    for (int of = 0; of < 8; ++of)
#pragma unroll
      for (int r = 0; r < 4; ++r) ep[lr * 132 + of * 16 + lg * 4 + r] = acc[qg][of][r];
    char* pon = (char*)(po16 + ((size_t)(kvq * 4 + n) * 4096 + q0 + wv * 32 + qg * 16) * 128);
#pragma unroll
    for (int it = 0; it < 4; ++it) {
      int e = lane + it * 64;
      int qq = e >> 4, c8 = e & 15;
      f32x4 va = *(const f32x4*)(ep + qq * 132 + c8 * 8);
      f32x4 vb = *(const f32x4*)(ep + qq * 132 + c8 * 8 + 4);
      f16x8 h;
#pragma unroll
      for (int j = 0; j < 4; ++j) { h[j] = (_Float16)va[j]; h[4 + j] = (_Float16)vb[j]; }
      *(f16x8*)(pon + (size_t)qq * 256 + c8 * 16) = h;
    }
    if (lg == 0)
      ml[(size_t)(kvq * 4 + n) * 4096 + q0 + wv * 32 + qg * 16 + lr] =
          float2{m[qg], qg == 0 ? L0 : L1};
  }
#undef STAGE
#undef KBUF
#undef GBUF
}

// ---------------- rec projection (MFMA) with FUSED 4-way merge + BN partial stats
__global__ __launch_bounds__(256) void rec_kernel(
    const _Float16* __restrict__ po16, const float2* __restrict__ ml,
    const _Float16* __restrict__ rw16, const float* __restrict__ rb,
    _Float16* __restrict__ rec16, float* __restrict__ partial) {
  const int pblk = blockIdx.x;  // 128 tiles of 32 positions
  const int n = blockIdx.y;
  const int p0 = pblk * 32;
  const int blin = n * 128 + pblk;  // 0..511
  const int tid = threadIdx.x, wv = tid >> 6, lane = tid & 63, lg = lane >> 4, lr = lane & 15;
  __shared__ __align__(16) char sB[8192];  // merged O tile [32 p][128 ci] fp16, swz ((p&7)<<4)

  // ---- fused merge staging: each thread merges one 16-ci segment of one row
  {
    const int row = tid >> 3;       // p within tile, 0..31
    const int c0 = (tid & 7) * 16;  // ci start
    float2 v[4];
    float M = -INFINITY;
#pragma unroll
    for (int k = 0; k < 4; ++k) {
      v[k] = ml[(size_t)(k * 4 + n) * 4096 + p0 + row];
      M = fmaxf(M, v[k].x);
    }
    float f[4], L = 0.f;
#pragma unroll
    for (int k = 0; k < 4; ++k) {
      f[k] = __expf(v[k].x - M);
      L += v[k].y * f[k];
    }
    const float inv = 1.0f / L;
    float o[16];
#pragma unroll
    for (int j = 0; j < 16; ++j) o[j] = 0.f;
#pragma unroll
    for (int k = 0; k < 4; ++k) {
      const _Float16* p = po16 + ((size_t)(k * 4 + n) * 4096 + p0 + row) * 128 + c0;
      f16x8 a = *(const f16x8*)p;
      f16x8 b = *(const f16x8*)(p + 8);
#pragma unroll
      for (int j = 0; j < 8; ++j) {
        o[j] += f[k] * (float)a[j];
        o[8 + j] += f[k] * (float)b[j];
      }
    }
    f16x8 h0, h1;
#pragma unroll
    for (int j = 0; j < 8; ++j) {
      h0[j] = (_Float16)(o[j] * inv);
      h1[j] = (_Float16)(o[8 + j] * inv);
    }
    char* dst = sB + row * 256;
    const int xr = (row & 7) << 4;
    *(f16x8*)(dst + ((c0 * 2) ^ xr)) = h0;
    *(f16x8*)(dst + ((c0 * 2 + 16) ^ xr)) = h1;
  }

  const int wc0 = wv * 64;
  f16x8 a[4][4];
#pragma unroll
  for (int mf = 0; mf < 4; ++mf)
#pragma unroll
    for (int kc = 0; kc < 4; ++kc)
      a[mf][kc] = *(const f16x8*)(rw16 + (size_t)(wc0 + mf * 16 + lr) * 128 + kc * 32 + lg * 8);
  __syncthreads();

  f32x4 acc[4][2];
#pragma unroll
  for (int mf = 0; mf < 4; ++mf) {
    acc[mf][0] = f32x4{0.f, 0.f, 0.f, 0.f};
    acc[mf][1] = f32x4{0.f, 0.f, 0.f, 0.f};
  }
  const int xorv = (lr & 7) << 4;
#pragma unroll
  for (int kc = 0; kc < 4; ++kc) {
    int cb = (kc * 64 + lg * 16) ^ xorv;
    f16x8 b0 = *(const f16x8*)(sB + lr * 256 + cb);
    f16x8 b1 = *(const f16x8*)(sB + (16 + lr) * 256 + cb);
#pragma unroll
    for (int mf = 0; mf < 4; ++mf) {
      acc[mf][0] = __builtin_amdgcn_mfma_f32_16x16x32_f16(a[mf][kc], b0, acc[mf][0], 0, 0, 0);
      acc[mf][1] = __builtin_amdgcn_mfma_f32_16x16x32_f16(a[mf][kc], b1, acc[mf][1], 0, 0, 0);
    }
  }
  float* pslot = partial + (size_t)blin * 512;
#pragma unroll
  for (int mf = 0; mf < 4; ++mf)
#pragma unroll
    for (int r = 0; r < 4; ++r) {
      int c = wc0 + mf * 16 + lg * 4 + r;
      float bias = rb[c];
      float v0 = acc[mf][0][r] + bias;
      float v1 = acc[mf][1][r] + bias;
      rec16[((size_t)n * 256 + c) * 4096 + p0 + lr] = (_Float16)v0;
      rec16[((size_t)n * 256 + c) * 4096 + p0 + 16 + lr] = (_Float16)v1;
      float s = v0 + v1, qd = v0 * v0 + v1 * v1;
      s += __shfl_xor(s, 1); qd += __shfl_xor(qd, 1);
      s += __shfl_xor(s, 2); qd += __shfl_xor(qd, 2);
      s += __shfl_xor(s, 4); qd += __shfl_xor(qd, 4);
      s += __shfl_xor(s, 8); qd += __shfl_xor(qd, 8);
      if (lr == 0) {
        pslot[c] = s;
        pslot[256 + c] = qd;
      }
    }
}

// ---------------- reduce per-block partials -> stats[512] (16 blocks, 8 lanes/stat)
__global__ __launch_bounds__(256) void stats_reduce(const float* __restrict__ partial,
                                                    float* __restrict__ stats) {
  const int tid = threadIdx.x;
  const int j = blockIdx.x * 32 + (tid >> 3);  // 0..511
  const int sub = tid & 7;
  float s = 0.f;
#pragma unroll 8
  for (int i = 0; i < 64; ++i) s += partial[(size_t)(i * 8 + sub) * 512 + j];
  s += __shfl_xor(s, 1);
  s += __shfl_xor(s, 2);
  s += __shfl_xor(s, 4);
  if (sub == 0) stats[j] = s;
}

// ---------------- BN apply + residual (reads fp16 rec result)
__global__ __launch_bounds__(256) void bn_kernel(
    const float* __restrict__ x, const float* __restrict__ gamma,
    const float* __restrict__ beta, const float* __restrict__ stats,
    const _Float16* __restrict__ rec16, float* __restrict__ out) {
  const size_t i4 = (size_t)blockIdx.x * 256 + threadIdx.x;
  const int c = (int)((i4 >> 10) & 255);
  const float inv = 1.f / 16384.f;
  const float mean = stats[c] * inv;
  const float var = stats[256 + c] * inv - mean * mean;
  const float gm = gamma[c] * rsqrtf(var + EPSV);
  const float bt = beta[c];
  f16x4 r4 = ((const f16x4*)rec16)[i4];
  float4 xv = ((const float4*)x)[i4];
  float4 o;
  o.x = xv.x + ((float)r4[0] - mean) * gm + bt;
  o.y = xv.y + ((float)r4[1] - mean) * gm + bt;
  o.z = xv.z + ((float)r4[2] - mean) * gm + bt;
  o.w = xv.w + ((float)r4[3] - mean) * gm + bt;
  ((float4*)out)[i4] = o;
}

extern "C" void kernel_launch(void* const* d_in, const int* in_sizes, int n_in,
                              void* d_out, int out_size, void* d_ws, size_t ws_size,
                              hipStream_t stream) {
  const float* x  = (const float*)d_in[0];
  const float* y  = (const float*)d_in[1];
  const float* tw = (const float*)d_in[2];
  const float* tb = (const float*)d_in[3];
  const float* pw = (const float*)d_in[4];
  const float* pb = (const float*)d_in[5];
  const float* gw = (const float*)d_in[6];
  const float* gb = (const float*)d_in[7];
  const float* rw = (const float*)d_in[8];
  const float* rb = (const float*)d_in[9];
  const float* gamma = (const float*)d_in[10];
  const float* beta  = (const float*)d_in[11];
  float* out = (float*)d_out;
  _Float16* xt    = (_Float16*)d_ws;        // 16MB [2][4][4096][256]; dead after proj
  _Float16* w16   = xt + 8388608;           // 256KB [4][32768]
  _Float16* th16  = w16 + 131072;           // 4MB [n][p][ci]
  _Float16* ph16  = th16 + 2097152;         // 4MB [n][p][ci]
  _Float16* g16   = ph16 + 2097152;         // 4MB [n] blocked [128][128][32]
  _Float16* rec16 = g16 + 2097152;          // 8MB [n][c][p]
  float* partial  = (float*)(rec16 + 4194304);  // 1MB [512][512]
  float* stats    = partial + 262144;           // 512 f32
  float2* ml      = (float2*)(stats + 512);     // 512KB [4][4][4096]
  _Float16* po16  = xt;                         // 16MB [4kvq][4n][4096][128] (aliases xt)
  _Float16* rw16 = w16 + 98304;
  pack_xy<<<dim3(512, 4, 3), 256, 0, stream>>>(x, y, tw, pw, gw, rw, xt, w16);
  proj_kernel<<<dim3(64, 12), 256, 0, stream>>>(xt, w16, tb, pb, gb, th16, ph16, g16);
  attn_kernel<<<dim3(512), 256, 0, stream>>>(th16, ph16, g16, po16, ml);
  rec_kernel<<<dim3(128, 4), 256, 0, stream>>>(po16, ml, rw16, rb, rec16, partial);
  stats_reduce<<<dim3(16), 256, 0, stream>>>(partial, stats);
  bn_kernel<<<dim3(4096), 256, 0, stream>>>(x, gamma, beta, stats, rec16, out);
}

// Round 18
// 112.307 us; speedup vs baseline: 1.4223x; 1.0031x over previous
//
#include <hip/hip_runtime.h>
#include <math.h>

#define EPSV 1e-5f

typedef __attribute__((ext_vector_type(8))) _Float16 f16x8;
typedef __attribute__((ext_vector_type(4))) _Float16 f16x4;
typedef __attribute__((ext_vector_type(4))) float f32x4;

typedef __attribute__((address_space(1))) const unsigned int as1_u32;
typedef __attribute__((address_space(3))) unsigned int as3_u32;

static __device__ __forceinline__ unsigned packh2(float a, float b) {
  auto v = __builtin_amdgcn_cvt_pkrtz(a, b);  // __fp16 ext_vector(2)
  return __builtin_bit_cast(unsigned, v);
}

// ---------------- pack x,y fp32 [n][c][p] -> fp16 transposed [src][n][p][c]
// z==2 blocks pack the four weight matrices fp32->fp16 instead.
__global__ __launch_bounds__(256) void pack_xy(
    const float* __restrict__ x, const float* __restrict__ y,
    const float* __restrict__ tw, const float* __restrict__ pw,
    const float* __restrict__ gw, const float* __restrict__ rw,
    _Float16* __restrict__ xt, _Float16* __restrict__ w16) {
  if (blockIdx.z == 2) {
    int i = (blockIdx.y * 512 + blockIdx.x) * 256 + threadIdx.x;
    if (i < 131072) {
      const float* s = i < 32768 ? tw : (i < 65536 ? pw : (i < 98304 ? gw : rw));
      w16[i] = (_Float16)s[i & 32767];
    }
    return;
  }
  const int n = blockIdx.y, s = blockIdx.z;
  const int g = blockIdx.x * 256 + threadIdx.x;  // 131072 per (n,s)
  const int p = g & 4095, c8 = g >> 12;          // c8 0..31
  const float* src = (s ? y : x) + ((size_t)n * 256 + c8 * 8) * 4096 + p;
  f16x8 v;
#pragma unroll
  for (int j = 0; j < 8; ++j) v[j] = (_Float16)src[(size_t)j * 4096];
  *(f16x8*)(xt + ((size_t)(s * 4 + n) * 4096 + p) * 256 + c8 * 8) = v;
}

// ---------------- projections via MFMA, PTILE=64 (768 blocks, 3/CU balanced).
// pr 0 (theta): -> [p][ci]; pr 1 (phi): -> [p][ci]; pr 2 (g): -> blocked [p/32][ci][32]
__global__ __launch_bounds__(256) void proj_kernel(
    const _Float16* __restrict__ xt, const _Float16* __restrict__ w16,
    const float* __restrict__ tb, const float* __restrict__ pb,
    const float* __restrict__ gb, _Float16* __restrict__ th16,
    _Float16* __restrict__ ph16, _Float16* __restrict__ g16) {
  const int ptile = blockIdx.x;  // 64 tiles of 64 positions
  const int z = blockIdx.y;      // 12 = 3 pr * 4 n
  const int pr = z >> 2, n = z & 3;
  const int p0 = ptile * 64;
  const int tid = threadIdx.x, wv = tid >> 6, lane = tid & 63, lg = lane >> 4, lr = lane & 15;

  __shared__ __align__(16) char sB[32768];  // X tile [64 p][256 c] fp16, swz ((p&7)<<4)

  const int srcn = (pr == 1 ? 4 : 0) + n;
  const char* src = (const char*)(xt + ((size_t)srcn * 4096 + p0) * 256);
#pragma unroll
  for (int ps = 0; ps < 8; ++ps) {
    int L = ps * 4096 + tid * 16;
    int row = L >> 9, col = L & 511;
    __builtin_amdgcn_global_load_lds((as1_u32*)(src + (size_t)row * 512 + (col ^ ((row & 7) << 4))),
                                     (as3_u32*)(sB + L), 16, 0, 0);
  }
  const _Float16* wp = w16 + pr * 32768;
  const float* bp = pr == 0 ? tb : (pr == 1 ? pb : gb);

  if (pr == 2) {
    const int o0 = wv * 32;
    f16x8 a[2][8];
#pragma unroll
    for (int mf = 0; mf < 2; ++mf)
#pragma unroll
      for (int kc = 0; kc < 8; ++kc)
        a[mf][kc] = *(const f16x8*)(wp + (size_t)(o0 + mf * 16 + lr) * 256 + kc * 32 + lg * 8);
    __syncthreads();
    f32x4 acc[2][4];
#pragma unroll
    for (int mf = 0; mf < 2; ++mf)
#pragma unroll
      for (int nf = 0; nf < 4; ++nf) acc[mf][nf] = f32x4{0.f, 0.f, 0.f, 0.f};
#pragma unroll
    for (int kc = 0; kc < 8; ++kc) {
      f16x8 bf[4];
#pragma unroll
      for (int nf = 0; nf < 4; ++nf)
        bf[nf] = *(const f16x8*)(sB + (nf * 16 + lr) * 512 + ((kc * 64 + lg * 16) ^ ((lr & 7) << 4)));
#pragma unroll
      for (int mf = 0; mf < 2; ++mf)
#pragma unroll
        for (int nf = 0; nf < 4; ++nf)
          acc[mf][nf] = __builtin_amdgcn_mfma_f32_16x16x32_f16(a[mf][kc], bf[nf], acc[mf][nf], 0, 0, 0);
    }
    // g blocked: [pblk=p>>5][ci][p&31], per n
    _Float16* out = g16 + (size_t)n * 524288;
#pragma unroll
    for (int mf = 0; mf < 2; ++mf)
#pragma unroll
      for (int r = 0; r < 4; ++r) {
        int o = o0 + mf * 16 + lg * 4 + r;
        float bias = bp[o];
#pragma unroll
        for (int nf = 0; nf < 4; ++nf) {
          int pp = p0 + nf * 16 + lr;
          out[(size_t)((pp >> 5) * 128 + o) * 32 + (pp & 31)] = (_Float16)(acc[mf][nf][r] + bias);
        }
      }
  } else {
    __syncthreads();
    // each wave owns 16 p-rows: rows wv*16 .. wv*16+15
    f32x4 acc[8];
#pragma unroll
    for (int nf = 0; nf < 8; ++nf) acc[nf] = f32x4{0.f, 0.f, 0.f, 0.f};
#pragma unroll 2
    for (int kc = 0; kc < 8; ++kc) {
      f16x8 bf[8];
#pragma unroll
      for (int nf = 0; nf < 8; ++nf)
        bf[nf] = *(const f16x8*)(wp + (size_t)(nf * 16 + lr) * 256 + kc * 32 + lg * 8);
      f16x8 af = *(const f16x8*)(sB + (wv * 16 + lr) * 512 + ((kc * 64 + lg * 16) ^ ((lr & 7) << 4)));
#pragma unroll
      for (int nf = 0; nf < 8; ++nf)
        acc[nf] = __builtin_amdgcn_mfma_f32_16x16x32_f16(af, bf[nf], acc[nf], 0, 0, 0);
    }
    _Float16* out = (pr == 0 ? th16 : ph16) + (size_t)n * 4096 * 128;
#pragma unroll
    for (int r = 0; r < 4; ++r) {
      int p = p0 + wv * 16 + lg * 4 + r;
#pragma unroll
      for (int nf = 0; nf < 8; ++nf) {
        int o = nf * 16 + lr;
        out[(size_t)p * 128 + o] = (_Float16)(acc[nf][r] + bp[o]);
      }
    }
  }
}

// ---------------- flash attention: 512 blocks, 4 waves x 32q (2 qg), KVBLK=64,
// each block owns one KV quarter (1024 kpos, 16 iters). REG-STAGED (T14):
// global->reg loads (no vmcnt drain at barriers) + ds_write into the dead buffer.
__global__ __launch_bounds__(256, 2) void attn_kernel(
    const _Float16* __restrict__ th16, const _Float16* __restrict__ ph16,
    const _Float16* __restrict__ g16, _Float16* __restrict__ po16,
    float2* __restrict__ ml) {
  const int lin = blockIdx.x;  // 512
  const int xcd = lin & 7;     // (n,kv-half) per XCD -> K/G slices L2-resident
  const int n = xcd >> 1;
  const int kvh = xcd & 1;
  const int rest = lin >> 3;   // 0..63
  const int qt = rest >> 1;    // 0..31
  const int kvq = kvh * 2 + (rest & 1);
  const int q0 = qt * 128;
  const int tid = threadIdx.x;
  const int wv = tid >> 6, lane = tid & 63, lg = lane >> 4, lr = lane & 15;
  const int kv0 = kvq * 1024;

  // K dbuf 2x16KB @0 | G dbuf 2x16KB @32768 | P 4wv x 2qg x 2KB @65536  (=80KB)
  __shared__ __align__(16) char smem[81920];
#define KBUF(B) (smem + (B) * 16384)
#define GBUF(B) (smem + 32768 + (B) * 16384)
  char* pB = smem + 65536 + wv * 4096;

  const _Float16* thn = th16 + (size_t)n * 4096 * 128;             // [p][ci]
  const char* phn = (const char*)(ph16 + (size_t)n * 4096 * 128);  // [p][ci]
  const char* ggn = (const char*)(g16 + (size_t)n * 524288);       // blocked [128][128][32]

  // pre-swizzled staging sources (same bytes/addresses as the gload_lds variant)
  const char* ksrc = phn + (size_t)kv0 * 256 + (tid >> 4) * 256 +
                     (((tid & 15) * 16) ^ (((tid >> 4) & 7) << 4));
  const char* gsrc = ggn + (size_t)kvq * 262144 + (tid >> 2) * 64 +
                     (((tid & 3) * 16) ^ (((tid >> 3) & 3) << 4));

  f32x4 kreg[4], greg[4];  // in-flight tile (reg staging)

#define LOADT(KT)                                                                        \
  do {                                                                                   \
    const char* ks = ksrc + (size_t)(KT) * 16384;                                        \
    const char* gs = gsrc + (size_t)(KT) * 16384;                                        \
    _Pragma("unroll") for (int i_ = 0; i_ < 4; ++i_) {                                   \
      kreg[i_] = *(const f32x4*)(ks + i_ * 4096);                                        \
      greg[i_] = *(const f32x4*)(gs + i_ * 4096);                                        \
    }                                                                                    \
  } while (0)

#define WRITET(B)                                                                        \
  do {                                                                                   \
    char* kd = KBUF(B) + tid * 16;                                                       \
    char* gd = GBUF(B) + tid * 16;                                                       \
    _Pragma("unroll") for (int i_ = 0; i_ < 4; ++i_) {                                   \
      *(f32x4*)(kd + i_ * 4096) = kreg[i_];                                              \
      *(f32x4*)(gd + i_ * 4096) = greg[i_];                                              \
    }                                                                                    \
  } while (0)

  // Q fragments (B-operand): B[k=ci][q=lr] per qg, vector loads from [p][ci]
  f16x8 qf[2][4];
#pragma unroll
  for (int qg = 0; qg < 2; ++qg)
#pragma unroll
    for (int ch = 0; ch < 4; ++ch)
      qf[qg][ch] = *(const f16x8*)(thn + (size_t)(q0 + wv * 32 + qg * 16 + lr) * 128 +
                                   ch * 32 + lg * 8);

  const int swzk = (lr & 7) << 4;         // K 256B rows
  const int swzg = ((lr >> 1) & 3) << 4;  // G 64B rows (balanced)
  const int swzp = (lr & 7) << 4;         // P 128B rows, 3-bit key

  f32x4 acc[2][8];
#pragma unroll
  for (int qg = 0; qg < 2; ++qg)
#pragma unroll
    for (int of = 0; of < 8; ++of) acc[qg][of] = f32x4{0.f, 0.f, 0.f, 0.f};
  float m[2] = {-INFINITY, -INFINITY};
  float lrow[2] = {0.f, 0.f};  // lane-partial; summed across lg at epilogue

  LOADT(0);
  WRITET(0);   // implicit vmcnt wait on kreg/greg use
  LOADT(1);    // tile 1 in flight across the barrier (registers -> no vmcnt drain)
  __syncthreads();

  for (int kt = 0; kt < 16; ++kt) {
    const int b = kt & 1;
    if (kt < 15) {
      WRITET(b ^ 1);              // tile kt+1 -> dead buffer (readers retired at last barrier)
      if (kt < 14) LOADT(kt + 2); // refill regs; lands during this + next iter
    }

    // QK: S^T[k=cf*16+lg*4+r][q=lr] per qg; each K frag feeds both qg
    const char* kb = KBUF(b);
    f32x4 s[4][2];
#pragma unroll
    for (int cf = 0; cf < 4; ++cf) {
      s[cf][0] = f32x4{0.f, 0.f, 0.f, 0.f};
      s[cf][1] = f32x4{0.f, 0.f, 0.f, 0.f};
    }
    __builtin_amdgcn_s_setprio(1);
#pragma unroll
    for (int cf = 0; cf < 4; ++cf) {
      const char* krow = kb + (cf * 16 + lr) * 256;
#pragma unroll
      for (int ch = 0; ch < 4; ++ch) {
        f16x8 kf = *(const f16x8*)(krow + ((ch * 64 + lg * 16) ^ swzk));
        s[cf][0] = __builtin_amdgcn_mfma_f32_16x16x32_f16(kf, qf[0][ch], s[cf][0], 0, 0, 0);
        s[cf][1] = __builtin_amdgcn_mfma_f32_16x16x32_f16(kf, qf[1][ch], s[cf][1], 0, 0, 0);
      }
    }
    __builtin_amdgcn_s_setprio(0);

    // lane-local max per qg; cross-lane reduce only when the __all gate fails
    float mt0 = s[0][0][0], mt1 = s[0][1][0];
#pragma unroll
    for (int cf = 0; cf < 4; ++cf)
#pragma unroll
      for (int r = 0; r < 4; ++r) {
        mt0 = fmaxf(mt0, s[cf][0][r]);
        mt1 = fmaxf(mt1, s[cf][1][r]);
      }
    bool ok = (mt0 <= m[0] + 8.0f) && (mt1 <= m[1] + 8.0f);
    if (!__all(ok)) {
      // group max over the 4 lanes sharing q (lg dimension)
      mt0 = fmaxf(mt0, __shfl_xor(mt0, 16)); mt0 = fmaxf(mt0, __shfl_xor(mt0, 32));
      mt1 = fmaxf(mt1, __shfl_xor(mt1, 16)); mt1 = fmaxf(mt1, __shfl_xor(mt1, 32));
      float mn0 = fmaxf(m[0], mt0), mn1 = fmaxf(m[1], mt1);
      float sc0 = __expf(m[0] - mn0), sc1 = __expf(m[1] - mn1);
#pragma unroll
      for (int of = 0; of < 8; ++of) { acc[0][of] *= sc0; acc[1][of] *= sc1; }
      lrow[0] *= sc0; lrow[1] *= sc1;
      m[0] = mn0; m[1] = mn1;
    }
#pragma unroll
    for (int qg = 0; qg < 2; ++qg) {
      char* prow = pB + qg * 2048 + lr * 128;
      float psum = 0.f;
#pragma unroll
      for (int cf = 0; cf < 4; ++cf) {
        float p0 = __expf(s[cf][qg][0] - m[qg]);
        float p1 = __expf(s[cf][qg][1] - m[qg]);
        float p2 = __expf(s[cf][qg][2] - m[qg]);
        float p3 = __expf(s[cf][qg][3] - m[qg]);
        psum += (p0 + p1) + (p2 + p3);
        unsigned long long w = (unsigned long long)packh2(p0, p1) |
                               ((unsigned long long)packh2(p2, p3) << 32);
        *(unsigned long long*)(prow + ((cf * 32 + lg * 8) ^ swzp)) = w;
      }
      lrow[qg] += psum;  // lane-partial; no shfl here
    }

    // PV: O^T[ci][q] += G * P^T per qg; each G frag feeds both qg
    const char* gb = GBUF(b);
#pragma unroll
    for (int kc = 0; kc < 2; ++kc) {
      f16x8 pf0 = *(const f16x8*)(pB + lr * 128 + ((kc * 64 + lg * 16) ^ swzp));
      f16x8 pf1 = *(const f16x8*)(pB + 2048 + lr * 128 + ((kc * 64 + lg * 16) ^ swzp));
      __builtin_amdgcn_s_setprio(1);
#pragma unroll
      for (int of = 0; of < 8; ++of) {
        f16x8 gf = *(const f16x8*)(gb + kc * 8192 + (of * 16 + lr) * 64 + ((lg * 16) ^ swzg));
        acc[0][of] = __builtin_amdgcn_mfma_f32_16x16x32_f16(gf, pf0, acc[0][of], 0, 0, 0);
        acc[1][of] = __builtin_amdgcn_mfma_f32_16x16x32_f16(gf, pf1, acc[1][of], 0, 0, 0);
      }
      __builtin_amdgcn_s_setprio(0);
    }
    __syncthreads();  // lgkm-only drain (DS); reg loads stay in flight
  }

  // finalize l: sum lane-partials across the 4 lanes sharing each q
  float L0 = lrow[0];
  L0 += __shfl_xor(L0, 16); L0 += __shfl_xor(L0, 32);
  float L1 = lrow[1];
  L1 += __shfl_xor(L1, 16); L1 += __shfl_xor(L1, 32);

  // epilogue: transpose O^T -> [q][ci] through LDS; fp16 partial + (m,l)
  float* ep = (float*)(smem + wv * 8448);  // 16 rows x 132 f32, per wave
#pragma unroll
  for (int qg = 0; qg < 2; ++qg) {
#pragma unroll
    for (int of = 0; of < 8; ++of)
#pragma unroll
      for (int r = 0; r < 4; ++r) ep[lr * 132 + of * 16 + lg * 4 + r] = acc[qg][of][r];
    char* pon = (char*)(po16 + ((size_t)(kvq * 4 + n) * 4096 + q0 + wv * 32 + qg * 16) * 128);
#pragma unroll
    for (int it = 0; it < 4; ++it) {
      int e = lane + it * 64;
      int qq = e >> 4, c8 = e & 15;
      f32x4 va = *(const f32x4*)(ep + qq * 132 + c8 * 8);
      f32x4 vb = *(const f32x4*)(ep + qq * 132 + c8 * 8 + 4);
      f16x8 h;
#pragma unroll
      for (int j = 0; j < 4; ++j) { h[j] = (_Float16)va[j]; h[4 + j] = (_Float16)vb[j]; }
      *(f16x8*)(pon + (size_t)qq * 256 + c8 * 16) = h;
    }
    if (lg == 0)
      ml[(size_t)(kvq * 4 + n) * 4096 + q0 + wv * 32 + qg * 16 + lr] =
          float2{m[qg], qg == 0 ? L0 : L1};
  }
#undef LOADT
#undef WRITET
#undef KBUF
#undef GBUF
}

// ---------------- rec projection (MFMA) with FUSED 4-way merge + BN partial stats
__global__ __launch_bounds__(256) void rec_kernel(
    const _Float16* __restrict__ po16, const float2* __restrict__ ml,
    const _Float16* __restrict__ rw16, const float* __restrict__ rb,
    _Float16* __restrict__ rec16, float* __restrict__ partial) {
  const int pblk = blockIdx.x;  // 128 tiles of 32 positions
  const int n = blockIdx.y;
  const int p0 = pblk * 32;
  const int blin = n * 128 + pblk;  // 0..511
  const int tid = threadIdx.x, wv = tid >> 6, lane = tid & 63, lg = lane >> 4, lr = lane & 15;
  __shared__ __align__(16) char sB[8192];  // merged O tile [32 p][128 ci] fp16, swz ((p&7)<<4)

  // ---- fused merge staging: each thread merges one 16-ci segment of one row
  {
    const int row = tid >> 3;       // p within tile, 0..31
    const int c0 = (tid & 7) * 16;  // ci start
    float2 v[4];
    float M = -INFINITY;
#pragma unroll
    for (int k = 0; k < 4; ++k) {
      v[k] = ml[(size_t)(k * 4 + n) * 4096 + p0 + row];
      M = fmaxf(M, v[k].x);
    }
    float f[4], L = 0.f;
#pragma unroll
    for (int k = 0; k < 4; ++k) {
      f[k] = __expf(v[k].x - M);
      L += v[k].y * f[k];
    }
    const float inv = 1.0f / L;
    float o[16];
#pragma unroll
    for (int j = 0; j < 16; ++j) o[j] = 0.f;
#pragma unroll
    for (int k = 0; k < 4; ++k) {
      const _Float16* p = po16 + ((size_t)(k * 4 + n) * 4096 + p0 + row) * 128 + c0;
      f16x8 a = *(const f16x8*)p;
      f16x8 b = *(const f16x8*)(p + 8);
#pragma unroll
      for (int j = 0; j < 8; ++j) {
        o[j] += f[k] * (float)a[j];
        o[8 + j] += f[k] * (float)b[j];
      }
    }
    f16x8 h0, h1;
#pragma unroll
    for (int j = 0; j < 8; ++j) {
      h0[j] = (_Float16)(o[j] * inv);
      h1[j] = (_Float16)(o[8 + j] * inv);
    }
    char* dst = sB + row * 256;
    const int xr = (row & 7) << 4;
    *(f16x8*)(dst + ((c0 * 2) ^ xr)) = h0;
    *(f16x8*)(dst + ((c0 * 2 + 16) ^ xr)) = h1;
  }

  const int wc0 = wv * 64;
  f16x8 a[4][4];
#pragma unroll
  for (int mf = 0; mf < 4; ++mf)
#pragma unroll
    for (int kc = 0; kc < 4; ++kc)
      a[mf][kc] = *(const f16x8*)(rw16 + (size_t)(wc0 + mf * 16 + lr) * 128 + kc * 32 + lg * 8);
  __syncthreads();

  f32x4 acc[4][2];
#pragma unroll
  for (int mf = 0; mf < 4; ++mf) {
    acc[mf][0] = f32x4{0.f, 0.f, 0.f, 0.f};
    acc[mf][1] = f32x4{0.f, 0.f, 0.f, 0.f};
  }
  const int xorv = (lr & 7) << 4;
#pragma unroll
  for (int kc = 0; kc < 4; ++kc) {
    int cb = (kc * 64 + lg * 16) ^ xorv;
    f16x8 b0 = *(const f16x8*)(sB + lr * 256 + cb);
    f16x8 b1 = *(const f16x8*)(sB + (16 + lr) * 256 + cb);
#pragma unroll
    for (int mf = 0; mf < 4; ++mf) {
      acc[mf][0] = __builtin_amdgcn_mfma_f32_16x16x32_f16(a[mf][kc], b0, acc[mf][0], 0, 0, 0);
      acc[mf][1] = __builtin_amdgcn_mfma_f32_16x16x32_f16(a[mf][kc], b1, acc[mf][1], 0, 0, 0);
    }
  }
  float* pslot = partial + (size_t)blin * 512;
#pragma unroll
  for (int mf = 0; mf < 4; ++mf)
#pragma unroll
    for (int r = 0; r < 4; ++r) {
      int c = wc0 + mf * 16 + lg * 4 + r;
      float bias = rb[c];
      float v0 = acc[mf][0][r] + bias;
      float v1 = acc[mf][1][r] + bias;
      rec16[((size_t)n * 256 + c) * 4096 + p0 + lr] = (_Float16)v0;
      rec16[((size_t)n * 256 + c) * 4096 + p0 + 16 + lr] = (_Float16)v1;
      float s = v0 + v1, qd = v0 * v0 + v1 * v1;
      s += __shfl_xor(s, 1); qd += __shfl_xor(qd, 1);
      s += __shfl_xor(s, 2); qd += __shfl_xor(qd, 2);
      s += __shfl_xor(s, 4); qd += __shfl_xor(qd, 4);
      s += __shfl_xor(s, 8); qd += __shfl_xor(qd, 8);
      if (lr == 0) {
        pslot[c] = s;
        pslot[256 + c] = qd;
      }
    }
}

// ---------------- reduce per-block partials -> stats[512] (16 blocks, 8 lanes/stat)
__global__ __launch_bounds__(256) void stats_reduce(const float* __restrict__ partial,
                                                    float* __restrict__ stats) {
  const int tid = threadIdx.x;
  const int j = blockIdx.x * 32 + (tid >> 3);  // 0..511
  const int sub = tid & 7;
  float s = 0.f;
#pragma unroll 8
  for (int i = 0; i < 64; ++i) s += partial[(size_t)(i * 8 + sub) * 512 + j];
  s += __shfl_xor(s, 1);
  s += __shfl_xor(s, 2);
  s += __shfl_xor(s, 4);
  if (sub == 0) stats[j] = s;
}

// ---------------- BN apply + residual (reads fp16 rec result)
__global__ __launch_bounds__(256) void bn_kernel(
    const float* __restrict__ x, const float* __restrict__ gamma,
    const float* __restrict__ beta, const float* __restrict__ stats,
    const _Float16* __restrict__ rec16, float* __restrict__ out) {
  const size_t i4 = (size_t)blockIdx.x * 256 + threadIdx.x;
  const int c = (int)((i4 >> 10) & 255);
  const float inv = 1.f / 16384.f;
  const float mean = stats[c] * inv;
  const float var = stats[256 + c] * inv - mean * mean;
  const float gm = gamma[c] * rsqrtf(var + EPSV);
  const float bt = beta[c];
  f16x4 r4 = ((const f16x4*)rec16)[i4];
  float4 xv = ((const float4*)x)[i4];
  float4 o;
  o.x = xv.x + ((float)r4[0] - mean) * gm + bt;
  o.y = xv.y + ((float)r4[1] - mean) * gm + bt;
  o.z = xv.z + ((float)r4[2] - mean) * gm + bt;
  o.w = xv.w + ((float)r4[3] - mean) * gm + bt;
  ((float4*)out)[i4] = o;
}

extern "C" void kernel_launch(void* const* d_in, const int* in_sizes, int n_in,
                              void* d_out, int out_size, void* d_ws, size_t ws_size,
                              hipStream_t stream) {
  const float* x  = (const float*)d_in[0];
  const float* y  = (const float*)d_in[1];
  const float* tw = (const float*)d_in[2];
  const float* tb = (const float*)d_in[3];
  const float* pw = (const float*)d_in[4];
  const float* pb = (const float*)d_in[5];
  const float* gw = (const float*)d_in[6];
  const float* gb = (const float*)d_in[7];
  const float* rw = (const float*)d_in[8];
  const float* rb = (const float*)d_in[9];
  const float* gamma = (const float*)d_in[10];
  const float* beta  = (const float*)d_in[11];
  float* out = (float*)d_out;
  _Float16* xt    = (_Float16*)d_ws;        // 16MB [2][4][4096][256]; dead after proj
  _Float16* w16   = xt + 8388608;           // 256KB [4][32768]
  _Float16* th16  = w16 + 131072;           // 4MB [n][p][ci]
  _Float16* ph16  = th16 + 2097152;         // 4MB [n][p][ci]
  _Float16* g16   = ph16 + 2097152;         // 4MB [n] blocked [128][128][32]
  _Float16* rec16 = g16 + 2097152;          // 8MB [n][c][p]
  float* partial  = (float*)(rec16 + 4194304);  // 1MB [512][512]
  float* stats    = partial + 262144;           // 512 f32
  float2* ml      = (float2*)(stats + 512);     // 512KB [4][4][4096]
  _Float16* po16  = xt;                         // 16MB [4kvq][4n][4096][128] (aliases xt)
  _Float16* rw16 = w16 + 98304;
  pack_xy<<<dim3(512, 4, 3), 256, 0, stream>>>(x, y, tw, pw, gw, rw, xt, w16);
  proj_kernel<<<dim3(64, 12), 256, 0, stream>>>(xt, w16, tb, pb, gb, th16, ph16, g16);
  attn_kernel<<<dim3(512), 256, 0, stream>>>(th16, ph16, g16, po16, ml);
  rec_kernel<<<dim3(128, 4), 256, 0, stream>>>(po16, ml, rw16, rb, rec16, partial);
  stats_reduce<<<dim3(16), 256, 0, stream>>>(partial, stats);
  bn_kernel<<<dim3(4096), 256, 0, stream>>>(x, gamma, beta, stats, rec16, out);
}